// Round 1
// baseline (1100.494 us; speedup 1.0000x reference)
//
#include <hip/hip_runtime.h>
#include <hip/hip_bf16.h>
#include <math.h>

#define HF 128          // hidden / input feature dim
#define GCOUNT 64       // graphs in batch
#define OUTF 64         // final output features
#define NEG 0.2f        // leaky relu slope

// ======================= CSR build (dst-indexed) =======================
__global__ void k_set_deg(int* deg, int n) {
    int i = blockIdx.x * 256 + threadIdx.x;
    if (i < n) deg[i] = 1;  // self loop contributes 1 incoming edge
}

__global__ void k_hist(const int* __restrict__ edst, int* deg, int ne) {
    int i = blockIdx.x * 256 + threadIdx.x;
    if (i < ne) atomicAdd(&deg[edst[i]], 1);
}

// in-place exclusive scan, chunk of 256 per block; bsums[b] = chunk total
__global__ void k_scan_partial(int* data, int* bsums, int n) {
    __shared__ int s[256];
    int i = blockIdx.x * 256 + threadIdx.x;
    int v = (i < n) ? data[i] : 0;
    s[threadIdx.x] = v;
    __syncthreads();
    int acc = v;
    for (int off = 1; off < 256; off <<= 1) {
        int t = (threadIdx.x >= off) ? s[threadIdx.x - off] : 0;
        __syncthreads();
        acc += t;
        s[threadIdx.x] = acc;
        __syncthreads();
    }
    if (i < n) data[i] = acc - v;          // exclusive within chunk
    if (threadIdx.x == 255) bsums[blockIdx.x] = acc;
}

__global__ void k_scan_block(int* b, int nb) {
    __shared__ int s[256];
    int v = (threadIdx.x < nb) ? b[threadIdx.x] : 0;
    s[threadIdx.x] = v;
    __syncthreads();
    int acc = v;
    for (int off = 1; off < 256; off <<= 1) {
        int t = (threadIdx.x >= off) ? s[threadIdx.x - off] : 0;
        __syncthreads();
        acc += t;
        s[threadIdx.x] = acc;
        __syncthreads();
    }
    if (threadIdx.x < nb) b[threadIdx.x] = acc - v;  // exclusive block offsets
}

__global__ void k_scan_add(int* data, const int* __restrict__ bsums, int n, int total) {
    int i = blockIdx.x * 256 + threadIdx.x;
    if (i < n) data[i] += bsums[blockIdx.x];
    if (i == 0) data[n] = total;           // rowptr[N] = E + N (known)
}

__global__ void k_copy(const int* __restrict__ a, int* b, int n) {
    int i = blockIdx.x * 256 + threadIdx.x;
    if (i < n) b[i] = a[i];
}

__global__ void k_fill(const int* __restrict__ esrc, const int* __restrict__ edst,
                       int* cur, int* colidx, int ne, int n) {
    int t = blockIdx.x * 256 + threadIdx.x;
    if (t >= ne + n) return;
    int s, d;
    if (t < ne) { s = esrc[t]; d = edst[t]; }
    else        { s = t - ne; d = s; }     // self loop
    int pos = atomicAdd(&cur[d], 1);
    colidx[pos] = s;
}

// ======================= fp32 GEMM: C[M x 128] = A[M x 128] @ B[128 x 128] (+bias) ==========
#define TM 64
#define TN 64
#define KC 32
__global__ __launch_bounds__(256) void k_gemm(const float* __restrict__ A,
                                              const float* __restrict__ B,
                                              const float* __restrict__ bias,
                                              float* __restrict__ C, int M) {
    __shared__ float As[KC][TM + 4];   // transposed A tile: As[k][m], +4 pad keeps 16B align
    __shared__ float Bs[KC][TN];
    const int m0 = blockIdx.x * TM;
    const int n0 = blockIdx.y * TN;
    const int tid = threadIdx.x;
    const int tx = tid & 15, ty = tid >> 4;

    float acc[4][4] = {};

    for (int kc = 0; kc < HF; kc += KC) {
        #pragma unroll
        for (int i = 0; i < 8; ++i) {
            int idx = tid + i * 256;
            int mm = idx >> 5;                  // 0..63
            int kk = idx & 31;                  // 0..31
            int row = m0 + mm;
            As[kk][mm] = (row < M) ? A[(size_t)row * HF + kc + kk] : 0.f;
        }
        #pragma unroll
        for (int i = 0; i < 8; ++i) {
            int idx = tid + i * 256;
            int kk = idx >> 6;                  // 0..31
            int nn = idx & 63;                  // 0..63
            Bs[kk][nn] = B[(size_t)(kc + kk) * HF + n0 + nn];
        }
        __syncthreads();
        #pragma unroll
        for (int k = 0; k < KC; ++k) {
            float4 a = *(const float4*)&As[k][4 * ty];
            float4 b = *(const float4*)&Bs[k][4 * tx];
            acc[0][0] = fmaf(a.x, b.x, acc[0][0]); acc[0][1] = fmaf(a.x, b.y, acc[0][1]);
            acc[0][2] = fmaf(a.x, b.z, acc[0][2]); acc[0][3] = fmaf(a.x, b.w, acc[0][3]);
            acc[1][0] = fmaf(a.y, b.x, acc[1][0]); acc[1][1] = fmaf(a.y, b.y, acc[1][1]);
            acc[1][2] = fmaf(a.y, b.z, acc[1][2]); acc[1][3] = fmaf(a.y, b.w, acc[1][3]);
            acc[2][0] = fmaf(a.z, b.x, acc[2][0]); acc[2][1] = fmaf(a.z, b.y, acc[2][1]);
            acc[2][2] = fmaf(a.z, b.z, acc[2][2]); acc[2][3] = fmaf(a.z, b.w, acc[2][3]);
            acc[3][0] = fmaf(a.w, b.x, acc[3][0]); acc[3][1] = fmaf(a.w, b.y, acc[3][1]);
            acc[3][2] = fmaf(a.w, b.z, acc[3][2]); acc[3][3] = fmaf(a.w, b.w, acc[3][3]);
        }
        __syncthreads();
    }

    float4 bb = make_float4(0.f, 0.f, 0.f, 0.f);
    if (bias) bb = *(const float4*)&bias[n0 + 4 * tx];
    #pragma unroll
    for (int i = 0; i < 4; ++i) {
        int row = m0 + 4 * ty + i;
        if (row < M) {
            float4 v = make_float4(acc[i][0] + bb.x, acc[i][1] + bb.y,
                                   acc[i][2] + bb.z, acc[i][3] + bb.w);
            *(float4*)&C[(size_t)row * HF + n0 + 4 * tx] = v;
        }
    }
}

// ======================= attention scalars: as_[i]=hp[i].a_s, ad_[i]=hp[i].a_d ==========
__global__ __launch_bounds__(256) void k_alpha(const float* __restrict__ hp,
                                               const float* __restrict__ a_s,
                                               const float* __restrict__ a_d,
                                               float* __restrict__ as_, float* __restrict__ ad_,
                                               int n) {
    int wave = (blockIdx.x * 256 + threadIdx.x) >> 6;
    int lane = threadIdx.x & 63;
    if (wave >= n) return;
    float2 v  = ((const float2*)(hp + (size_t)wave * HF))[lane];
    float2 s2 = ((const float2*)a_s)[lane];
    float2 d2 = ((const float2*)a_d)[lane];
    float ps = v.x * s2.x + v.y * s2.y;
    float pd = v.x * d2.x + v.y * d2.y;
    for (int off = 32; off; off >>= 1) {
        ps += __shfl_xor(ps, off);
        pd += __shfl_xor(pd, off);
    }
    if (lane == 0) { as_[wave] = ps; ad_[wave] = pd; }
}

// ======================= per-dst softmax aggregation (one wave per node) ==========
__global__ __launch_bounds__(256) void k_agg(const int* __restrict__ rowptr,
                                             const int* __restrict__ colidx,
                                             const float* __restrict__ hp,
                                             const float* __restrict__ as_,
                                             const float* __restrict__ ad_,
                                             const float* __restrict__ bl,
                                             float* __restrict__ hout,
                                             int n, int relu) {
    int wave = (blockIdx.x * 256 + threadIdx.x) >> 6;
    int lane = threadIdx.x & 63;
    if (wave >= n) return;
    int beg = rowptr[wave], end = rowptr[wave + 1];
    float adi = ad_[wave];

    // pass 1a: max over incoming edges
    float m = -1e30f;
    for (int j = beg + lane; j < end; j += 64) {
        float e = as_[colidx[j]] + adi;
        e = e > 0.f ? e : NEG * e;
        m = fmaxf(m, e);
    }
    for (int off = 32; off; off >>= 1) m = fmaxf(m, __shfl_xor(m, off));

    // pass 1b: denom
    float ssum = 0.f;
    for (int j = beg + lane; j < end; j += 64) {
        float e = as_[colidx[j]] + adi;
        e = e > 0.f ? e : NEG * e;
        ssum += __expf(e - m);
    }
    for (int off = 32; off; off >>= 1) ssum += __shfl_xor(ssum, off);
    float inv = 1.f / ssum;

    // pass 2: weighted feature gather (2 dims per lane)
    float acc0 = 0.f, acc1 = 0.f;
    for (int j = beg; j < end; ++j) {
        int srcn = colidx[j];                   // wave-uniform broadcast
        float e = as_[srcn] + adi;
        e = e > 0.f ? e : NEG * e;
        float w = __expf(e - m) * inv;
        float2 v = ((const float2*)(hp + (size_t)srcn * HF))[lane];
        acc0 = fmaf(w, v.x, acc0);
        acc1 = fmaf(w, v.y, acc1);
    }
    float2 bb = ((const float2*)bl)[lane];
    acc0 += bb.x; acc1 += bb.y;
    if (relu) { acc0 = fmaxf(acc0, 0.f); acc1 = fmaxf(acc1, 0.f); }
    ((float2*)(hout + (size_t)wave * HF))[lane] = make_float2(acc0, acc1);
}

// ======================= pooling over sorted batch ==========
__global__ void k_starts_init(int* starts, int n) {
    int i = threadIdx.x;
    if (i <= GCOUNT) starts[i] = n;
}
__global__ void k_starts_min(const int* __restrict__ batch, int* starts, int n) {
    int i = blockIdx.x * 256 + threadIdx.x;
    if (i < n) atomicMin(&starts[batch[i]], i);
}
__global__ void k_starts_fix(int* starts) {
    if (threadIdx.x == 0) {
        for (int g = GCOUNT - 1; g >= 0; --g)
            if (starts[g] > starts[g + 1]) starts[g] = starts[g + 1];
    }
}
__global__ void k_pool(const float* __restrict__ h, const int* __restrict__ starts,
                       float* __restrict__ pooled) {
    int g = blockIdx.x, t = threadIdx.x;   // 128 threads
    int b = starts[g], e = starts[g + 1];
    float s = 0.f;
    for (int i = b; i < e; ++i) s += h[(size_t)i * HF + t];
    pooled[g * HF + t] = s;
}
__global__ void k_final(const float* __restrict__ pooled, const float* __restrict__ Wf,
                        const float* __restrict__ bf, float* __restrict__ out) {
    int g = blockIdx.x, o = threadIdx.x;   // 64 threads
    float acc = bf[o];
    #pragma unroll 8
    for (int k = 0; k < HF; ++k) acc = fmaf(pooled[g * HF + k], Wf[k * OUTF + o], acc);
    out[g * OUTF + o] = acc;
}

// ======================= launch =======================
extern "C" void kernel_launch(void* const* d_in, const int* in_sizes, int n_in,
                              void* d_out, int out_size, void* d_ws, size_t ws_size,
                              hipStream_t stream) {
    const float* x      = (const float*)d_in[0];
    const int*   edge   = (const int*)d_in[1];
    const int*   batch  = (const int*)d_in[2];
    const float* W0     = (const float*)d_in[3];
    const float* b0     = (const float*)d_in[4];
    const float* Wl     = (const float*)d_in[5];
    const float* a_src  = (const float*)d_in[6];
    const float* a_dst  = (const float*)d_in[7];
    const float* bl     = (const float*)d_in[8];
    const float* Wf     = (const float*)d_in[9];
    const float* bf     = (const float*)d_in[10];
    float* out = (float*)d_out;

    const int N  = in_sizes[2];
    const int E  = in_sizes[1] / 2;
    const int Et = E + N;
    const int L  = 3;

    // workspace layout
    char* ws = (char*)d_ws;
    size_t off = 0;
    auto alloc = [&](size_t bytes) { char* p = ws + off; off += (bytes + 255) & ~(size_t)255; return p; };
    float* h      = (float*)alloc((size_t)N * HF * 4);
    float* hp     = (float*)alloc((size_t)N * HF * 4);
    float* as_    = (float*)alloc((size_t)N * 4);
    float* ad_    = (float*)alloc((size_t)N * 4);
    int*   rowptr = (int*)alloc((size_t)(N + 1) * 4);
    int*   cur    = (int*)alloc((size_t)N * 4);
    int*   colidx = (int*)alloc((size_t)Et * 4);
    int*   bsums  = (int*)alloc(1024);
    int*   starts = (int*)alloc((size_t)(GCOUNT + 1) * 4);
    float* pooled = (float*)alloc((size_t)GCOUNT * HF * 4);
    (void)ws_size; (void)n_in; (void)out_size;

    const int nb256  = (N + 255) / 256;          // 196
    const int eb256  = (E + 255) / 256;
    const int tb256  = (Et + 255) / 256;
    const int wb4    = (N + 3) / 4;              // wave-per-node kernels

    const int* esrc = edge;
    const int* edst = edge + E;

    // --- build dst-CSR (reused across all 3 layers) ---
    k_set_deg<<<nb256, 256, 0, stream>>>(rowptr, N);
    k_hist<<<eb256, 256, 0, stream>>>(edst, rowptr, E);
    k_scan_partial<<<nb256, 256, 0, stream>>>(rowptr, bsums, N);
    k_scan_block<<<1, 256, 0, stream>>>(bsums, nb256);
    k_scan_add<<<nb256, 256, 0, stream>>>(rowptr, bsums, N, Et);
    k_copy<<<nb256, 256, 0, stream>>>(rowptr, cur, N);
    k_fill<<<tb256, 256, 0, stream>>>(esrc, edst, cur, colidx, E, N);

    // --- h = x @ W0 + b0 ---
    dim3 ggrid((N + TM - 1) / TM, HF / TN);
    k_gemm<<<ggrid, 256, 0, stream>>>(x, W0, b0, h, N);

    // --- GAT layers ---
    for (int l = 0; l < L; ++l) {
        k_gemm<<<ggrid, 256, 0, stream>>>(h, Wl + (size_t)l * HF * HF, nullptr, hp, N);
        k_alpha<<<wb4, 256, 0, stream>>>(hp, a_src + l * HF, a_dst + l * HF, as_, ad_, N);
        k_agg<<<wb4, 256, 0, stream>>>(rowptr, colidx, hp, as_, ad_, bl + l * HF, h, N,
                                       (l < L - 1) ? 1 : 0);
    }

    // --- pooling + final linear ---
    k_starts_init<<<1, 128, 0, stream>>>(starts, N);
    k_starts_min<<<nb256, 256, 0, stream>>>(batch, starts, N);
    k_starts_fix<<<1, 64, 0, stream>>>(starts);
    k_pool<<<GCOUNT, HF, 0, stream>>>(h, starts, pooled);
    k_final<<<GCOUNT, OUTF, 0, stream>>>(pooled, Wf, bf, out);
}

// Round 2
// 865.455 us; speedup vs baseline: 1.2716x; 1.2716x over previous
//
#include <hip/hip_runtime.h>
#include <hip/hip_bf16.h>
#include <math.h>

#define HF 128          // hidden / input feature dim
#define GCOUNT 64       // graphs in batch
#define OUTF 64         // final output features
#define NEG 0.2f        // leaky relu slope

// ======================= CSR build (dst-indexed) =======================
__global__ void k_set_deg(int* deg, int n) {
    int i = blockIdx.x * 256 + threadIdx.x;
    if (i < n) deg[i] = 1;  // self loop contributes 1 incoming edge
}

__global__ void k_hist(const int* __restrict__ edst, int* deg, int ne) {
    int i = blockIdx.x * 256 + threadIdx.x;
    if (i < ne) atomicAdd(&deg[edst[i]], 1);
}

// in-place exclusive scan, chunk of 256 per block; bsums[b] = chunk total
__global__ void k_scan_partial(int* data, int* bsums, int n) {
    __shared__ int s[256];
    int i = blockIdx.x * 256 + threadIdx.x;
    int v = (i < n) ? data[i] : 0;
    s[threadIdx.x] = v;
    __syncthreads();
    int acc = v;
    for (int off = 1; off < 256; off <<= 1) {
        int t = (threadIdx.x >= off) ? s[threadIdx.x - off] : 0;
        __syncthreads();
        acc += t;
        s[threadIdx.x] = acc;
        __syncthreads();
    }
    if (i < n) data[i] = acc - v;          // exclusive within chunk
    if (threadIdx.x == 255) bsums[blockIdx.x] = acc;
}

__global__ void k_scan_block(int* b, int nb) {
    __shared__ int s[256];
    int v = (threadIdx.x < nb) ? b[threadIdx.x] : 0;
    s[threadIdx.x] = v;
    __syncthreads();
    int acc = v;
    for (int off = 1; off < 256; off <<= 1) {
        int t = (threadIdx.x >= off) ? s[threadIdx.x - off] : 0;
        __syncthreads();
        acc += t;
        s[threadIdx.x] = acc;
        __syncthreads();
    }
    if (threadIdx.x < nb) b[threadIdx.x] = acc - v;  // exclusive block offsets
}

__global__ void k_scan_add(int* data, const int* __restrict__ bsums, int n, int total) {
    int i = blockIdx.x * 256 + threadIdx.x;
    if (i < n) data[i] += bsums[blockIdx.x];
    if (i == 0) data[n] = total;           // rowptr[N] = E + N (known)
}

__global__ void k_copy(const int* __restrict__ a, int* b, int n) {
    int i = blockIdx.x * 256 + threadIdx.x;
    if (i < n) b[i] = a[i];
}

__global__ void k_fill(const int* __restrict__ esrc, const int* __restrict__ edst,
                       int* cur, int* colidx, int ne, int n) {
    int t = blockIdx.x * 256 + threadIdx.x;
    if (t >= ne + n) return;
    int s, d;
    if (t < ne) { s = esrc[t]; d = edst[t]; }
    else        { s = t - ne; d = s; }     // self loop
    int pos = atomicAdd(&cur[d], 1);
    colidx[pos] = s;
}

// ======================= fp32 GEMM: C[M x 128] = A[M x 128] @ B[128 x 128] (+bias) ==========
#define TM 64
#define TN 64
#define KC 32
__global__ __launch_bounds__(256) void k_gemm(const float* __restrict__ A,
                                              const float* __restrict__ B,
                                              const float* __restrict__ bias,
                                              float* __restrict__ C, int M) {
    __shared__ float As[KC][TM + 4];   // transposed A tile: As[k][m], +4 pad keeps 16B align
    __shared__ float Bs[KC][TN];
    const int m0 = blockIdx.x * TM;
    const int n0 = blockIdx.y * TN;
    const int tid = threadIdx.x;
    const int tx = tid & 15, ty = tid >> 4;

    float acc[4][4] = {};

    for (int kc = 0; kc < HF; kc += KC) {
        #pragma unroll
        for (int i = 0; i < 8; ++i) {
            int idx = tid + i * 256;
            int mm = idx >> 5;                  // 0..63
            int kk = idx & 31;                  // 0..31
            int row = m0 + mm;
            As[kk][mm] = (row < M) ? A[(size_t)row * HF + kc + kk] : 0.f;
        }
        #pragma unroll
        for (int i = 0; i < 8; ++i) {
            int idx = tid + i * 256;
            int kk = idx >> 6;                  // 0..31
            int nn = idx & 63;                  // 0..63
            Bs[kk][nn] = B[(size_t)(kc + kk) * HF + n0 + nn];
        }
        __syncthreads();
        #pragma unroll
        for (int k = 0; k < KC; ++k) {
            float4 a = *(const float4*)&As[k][4 * ty];
            float4 b = *(const float4*)&Bs[k][4 * tx];
            acc[0][0] = fmaf(a.x, b.x, acc[0][0]); acc[0][1] = fmaf(a.x, b.y, acc[0][1]);
            acc[0][2] = fmaf(a.x, b.z, acc[0][2]); acc[0][3] = fmaf(a.x, b.w, acc[0][3]);
            acc[1][0] = fmaf(a.y, b.x, acc[1][0]); acc[1][1] = fmaf(a.y, b.y, acc[1][1]);
            acc[1][2] = fmaf(a.y, b.z, acc[1][2]); acc[1][3] = fmaf(a.y, b.w, acc[1][3]);
            acc[2][0] = fmaf(a.z, b.x, acc[2][0]); acc[2][1] = fmaf(a.z, b.y, acc[2][1]);
            acc[2][2] = fmaf(a.z, b.z, acc[2][2]); acc[2][3] = fmaf(a.z, b.w, acc[2][3]);
            acc[3][0] = fmaf(a.w, b.x, acc[3][0]); acc[3][1] = fmaf(a.w, b.y, acc[3][1]);
            acc[3][2] = fmaf(a.w, b.z, acc[3][2]); acc[3][3] = fmaf(a.w, b.w, acc[3][3]);
        }
        __syncthreads();
    }

    float4 bb = make_float4(0.f, 0.f, 0.f, 0.f);
    if (bias) bb = *(const float4*)&bias[n0 + 4 * tx];
    #pragma unroll
    for (int i = 0; i < 4; ++i) {
        int row = m0 + 4 * ty + i;
        if (row < M) {
            float4 v = make_float4(acc[i][0] + bb.x, acc[i][1] + bb.y,
                                   acc[i][2] + bb.z, acc[i][3] + bb.w);
            *(float4*)&C[(size_t)row * HF + n0 + 4 * tx] = v;
        }
    }
}

// ======================= attention scalars: as_[i]=hp[i].a_s, ad_[i]=hp[i].a_d ==========
__global__ __launch_bounds__(256) void k_alpha(const float* __restrict__ hp,
                                               const float* __restrict__ a_s,
                                               const float* __restrict__ a_d,
                                               float* __restrict__ as_, float* __restrict__ ad_,
                                               int n) {
    int wave = (blockIdx.x * 256 + threadIdx.x) >> 6;
    int lane = threadIdx.x & 63;
    if (wave >= n) return;
    float2 v  = ((const float2*)(hp + (size_t)wave * HF))[lane];
    float2 s2 = ((const float2*)a_s)[lane];
    float2 d2 = ((const float2*)a_d)[lane];
    float ps = v.x * s2.x + v.y * s2.y;
    float pd = v.x * d2.x + v.y * d2.y;
    for (int off = 32; off; off >>= 1) {
        ps += __shfl_xor(ps, off);
        pd += __shfl_xor(pd, off);
    }
    if (lane == 0) { as_[wave] = ps; ad_[wave] = pd; }
}

// ======================= per-dst softmax aggregation (one wave per node) ==========
__global__ __launch_bounds__(256) void k_agg(const int* __restrict__ rowptr,
                                             const int* __restrict__ colidx,
                                             const float* __restrict__ hp,
                                             const float* __restrict__ as_,
                                             const float* __restrict__ ad_,
                                             const float* __restrict__ bl,
                                             float* __restrict__ hout,
                                             int n, int relu) {
    int wave = (blockIdx.x * 256 + threadIdx.x) >> 6;
    int lane = threadIdx.x & 63;
    if (wave >= n) return;
    int beg = rowptr[wave], end = rowptr[wave + 1];
    float adi = ad_[wave];

    // pass 1a: max over incoming edges
    float m = -1e30f;
    for (int j = beg + lane; j < end; j += 64) {
        float e = as_[colidx[j]] + adi;
        e = e > 0.f ? e : NEG * e;
        m = fmaxf(m, e);
    }
    for (int off = 32; off; off >>= 1) m = fmaxf(m, __shfl_xor(m, off));

    // pass 1b: denom
    float ssum = 0.f;
    for (int j = beg + lane; j < end; j += 64) {
        float e = as_[colidx[j]] + adi;
        e = e > 0.f ? e : NEG * e;
        ssum += __expf(e - m);
    }
    for (int off = 32; off; off >>= 1) ssum += __shfl_xor(ssum, off);
    float inv = 1.f / ssum;

    // pass 2: weighted feature gather (2 dims per lane)
    float acc0 = 0.f, acc1 = 0.f;
    for (int j = beg; j < end; ++j) {
        int srcn = colidx[j];                   // wave-uniform broadcast
        float e = as_[srcn] + adi;
        e = e > 0.f ? e : NEG * e;
        float w = __expf(e - m) * inv;
        float2 v = ((const float2*)(hp + (size_t)srcn * HF))[lane];
        acc0 = fmaf(w, v.x, acc0);
        acc1 = fmaf(w, v.y, acc1);
    }
    float2 bb = ((const float2*)bl)[lane];
    acc0 += bb.x; acc1 += bb.y;
    if (relu) { acc0 = fmaxf(acc0, 0.f); acc1 = fmaxf(acc1, 0.f); }
    ((float2*)(hout + (size_t)wave * HF))[lane] = make_float2(acc0, acc1);
}

// ======================= pooling over sorted batch ==========
__global__ void k_starts_init(int* starts, int n) {
    int i = threadIdx.x;
    if (i <= GCOUNT) starts[i] = n;
}
// batch is SORTED: group g starts where batch[i] != batch[i-1]. No atomics.
__global__ void k_starts_bound(const int* __restrict__ batch, int* starts, int n) {
    int i = blockIdx.x * 256 + threadIdx.x;
    if (i >= n) return;
    int b = batch[i];
    if (i == 0) starts[b] = 0;
    else if (batch[i - 1] != b) starts[b] = i;
}
__global__ void k_starts_fix(int* starts) {
    if (threadIdx.x == 0) {
        for (int g = GCOUNT - 1; g >= 0; --g)
            if (starts[g] > starts[g + 1]) starts[g] = starts[g + 1];
    }
}
__global__ void k_pool(const float* __restrict__ h, const int* __restrict__ starts,
                       float* __restrict__ pooled) {
    int g = blockIdx.x, t = threadIdx.x;   // 128 threads
    int b = starts[g], e = starts[g + 1];
    float s = 0.f;
    for (int i = b; i < e; ++i) s += h[(size_t)i * HF + t];
    pooled[g * HF + t] = s;
}
__global__ void k_final(const float* __restrict__ pooled, const float* __restrict__ Wf,
                        const float* __restrict__ bf, float* __restrict__ out) {
    int g = blockIdx.x, o = threadIdx.x;   // 64 threads
    float acc = bf[o];
    #pragma unroll 8
    for (int k = 0; k < HF; ++k) acc = fmaf(pooled[g * HF + k], Wf[k * OUTF + o], acc);
    out[g * OUTF + o] = acc;
}

// ======================= launch =======================
extern "C" void kernel_launch(void* const* d_in, const int* in_sizes, int n_in,
                              void* d_out, int out_size, void* d_ws, size_t ws_size,
                              hipStream_t stream) {
    const float* x      = (const float*)d_in[0];
    const int*   edge   = (const int*)d_in[1];
    const int*   batch  = (const int*)d_in[2];
    const float* W0     = (const float*)d_in[3];
    const float* b0     = (const float*)d_in[4];
    const float* Wl     = (const float*)d_in[5];
    const float* a_src  = (const float*)d_in[6];
    const float* a_dst  = (const float*)d_in[7];
    const float* bl     = (const float*)d_in[8];
    const float* Wf     = (const float*)d_in[9];
    const float* bf     = (const float*)d_in[10];
    float* out = (float*)d_out;

    const int N  = in_sizes[2];
    const int E  = in_sizes[1] / 2;
    const int Et = E + N;
    const int L  = 3;

    // workspace layout
    char* ws = (char*)d_ws;
    size_t off = 0;
    auto alloc = [&](size_t bytes) { char* p = ws + off; off += (bytes + 255) & ~(size_t)255; return p; };
    float* h      = (float*)alloc((size_t)N * HF * 4);
    float* hp     = (float*)alloc((size_t)N * HF * 4);
    float* as_    = (float*)alloc((size_t)N * 4);
    float* ad_    = (float*)alloc((size_t)N * 4);
    int*   rowptr = (int*)alloc((size_t)(N + 1) * 4);
    int*   cur    = (int*)alloc((size_t)N * 4);
    int*   colidx = (int*)alloc((size_t)Et * 4);
    int*   bsums  = (int*)alloc(1024);
    int*   starts = (int*)alloc((size_t)(GCOUNT + 1) * 4);
    float* pooled = (float*)alloc((size_t)GCOUNT * HF * 4);
    (void)ws_size; (void)n_in; (void)out_size;

    const int nb256  = (N + 255) / 256;          // 196
    const int eb256  = (E + 255) / 256;
    const int tb256  = (Et + 255) / 256;
    const int wb4    = (N + 3) / 4;              // wave-per-node kernels

    const int* esrc = edge;
    const int* edst = edge + E;

    // --- build dst-CSR (reused across all 3 layers) ---
    k_set_deg<<<nb256, 256, 0, stream>>>(rowptr, N);
    k_hist<<<eb256, 256, 0, stream>>>(edst, rowptr, E);
    k_scan_partial<<<nb256, 256, 0, stream>>>(rowptr, bsums, N);
    k_scan_block<<<1, 256, 0, stream>>>(bsums, nb256);
    k_scan_add<<<nb256, 256, 0, stream>>>(rowptr, bsums, N, Et);
    k_copy<<<nb256, 256, 0, stream>>>(rowptr, cur, N);
    k_fill<<<tb256, 256, 0, stream>>>(esrc, edst, cur, colidx, E, N);

    // --- h = x @ W0 + b0 ---
    dim3 ggrid((N + TM - 1) / TM, HF / TN);
    k_gemm<<<ggrid, 256, 0, stream>>>(x, W0, b0, h, N);

    // --- GAT layers ---
    for (int l = 0; l < L; ++l) {
        k_gemm<<<ggrid, 256, 0, stream>>>(h, Wl + (size_t)l * HF * HF, nullptr, hp, N);
        k_alpha<<<wb4, 256, 0, stream>>>(hp, a_src + l * HF, a_dst + l * HF, as_, ad_, N);
        k_agg<<<wb4, 256, 0, stream>>>(rowptr, colidx, hp, as_, ad_, bl + l * HF, h, N,
                                       (l < L - 1) ? 1 : 0);
    }

    // --- pooling + final linear ---
    k_starts_init<<<1, 128, 0, stream>>>(starts, N);
    k_starts_bound<<<nb256, 256, 0, stream>>>(batch, starts, N);
    k_starts_fix<<<1, 64, 0, stream>>>(starts);
    k_pool<<<GCOUNT, HF, 0, stream>>>(h, starts, pooled);
    k_final<<<GCOUNT, OUTF, 0, stream>>>(pooled, Wf, bf, out);
}

// Round 3
// 694.463 us; speedup vs baseline: 1.5847x; 1.2462x over previous
//
#include <hip/hip_runtime.h>
#include <hip/hip_bf16.h>
#include <math.h>

#define HF 128          // hidden / input feature dim
#define GCOUNT 64       // graphs in batch
#define OUTF 64         // final output features
#define NEG 0.2f        // leaky relu slope

// ======================= CSR build (dst-indexed) =======================
__global__ void k_set_deg(int* deg, int n) {
    int i = blockIdx.x * 256 + threadIdx.x;
    if (i < n) deg[i] = 1;  // self loop contributes 1 incoming edge
}

__global__ void k_hist(const int* __restrict__ edst, int* deg, int ne) {
    int i = blockIdx.x * 256 + threadIdx.x;
    if (i < ne) atomicAdd(&deg[edst[i]], 1);
}

// in-place exclusive scan, chunk of 256 per block; bsums[b] = chunk total
__global__ void k_scan_partial(int* data, int* bsums, int n) {
    __shared__ int s[256];
    int i = blockIdx.x * 256 + threadIdx.x;
    int v = (i < n) ? data[i] : 0;
    s[threadIdx.x] = v;
    __syncthreads();
    int acc = v;
    for (int off = 1; off < 256; off <<= 1) {
        int t = (threadIdx.x >= off) ? s[threadIdx.x - off] : 0;
        __syncthreads();
        acc += t;
        s[threadIdx.x] = acc;
        __syncthreads();
    }
    if (i < n) data[i] = acc - v;          // exclusive within chunk
    if (threadIdx.x == 255) bsums[blockIdx.x] = acc;
}

__global__ void k_scan_block(int* b, int nb) {
    __shared__ int s[256];
    int v = (threadIdx.x < nb) ? b[threadIdx.x] : 0;
    s[threadIdx.x] = v;
    __syncthreads();
    int acc = v;
    for (int off = 1; off < 256; off <<= 1) {
        int t = (threadIdx.x >= off) ? s[threadIdx.x - off] : 0;
        __syncthreads();
        acc += t;
        s[threadIdx.x] = acc;
        __syncthreads();
    }
    if (threadIdx.x < nb) b[threadIdx.x] = acc - v;  // exclusive block offsets
}

__global__ void k_scan_add(int* data, const int* __restrict__ bsums, int n, int total) {
    int i = blockIdx.x * 256 + threadIdx.x;
    if (i < n) data[i] += bsums[blockIdx.x];
    if (i == 0) data[n] = total;           // rowptr[N] = E + N (known)
}

__global__ void k_copy(const int* __restrict__ a, int* b, int n) {
    int i = blockIdx.x * 256 + threadIdx.x;
    if (i < n) b[i] = a[i];
}

__global__ void k_fill(const int* __restrict__ esrc, const int* __restrict__ edst,
                       int* cur, int* colidx, int ne, int n) {
    int t = blockIdx.x * 256 + threadIdx.x;
    if (t >= ne + n) return;
    int s, d;
    if (t < ne) { s = esrc[t]; d = edst[t]; }
    else        { s = t - ne; d = s; }     // self loop
    int pos = atomicAdd(&cur[d], 1);
    colidx[pos] = s;
}

// ======================= fp32 GEMM: C[M x 128] = A[M x 128] @ B[128 x 128] (+bias) ==========
#define TM 64
#define TN 64
#define KC 32
__global__ __launch_bounds__(256) void k_gemm(const float* __restrict__ A,
                                              const float* __restrict__ B,
                                              const float* __restrict__ bias,
                                              float* __restrict__ C, int M) {
    __shared__ float As[KC][TM + 4];   // transposed A tile: As[k][m], +4 pad keeps 16B align
    __shared__ float Bs[KC][TN];
    const int m0 = blockIdx.x * TM;
    const int n0 = blockIdx.y * TN;
    const int tid = threadIdx.x;
    const int tx = tid & 15, ty = tid >> 4;

    float acc[4][4] = {};

    for (int kc = 0; kc < HF; kc += KC) {
        #pragma unroll
        for (int i = 0; i < 8; ++i) {
            int idx = tid + i * 256;
            int mm = idx >> 5;                  // 0..63
            int kk = idx & 31;                  // 0..31
            int row = m0 + mm;
            As[kk][mm] = (row < M) ? A[(size_t)row * HF + kc + kk] : 0.f;
        }
        #pragma unroll
        for (int i = 0; i < 8; ++i) {
            int idx = tid + i * 256;
            int kk = idx >> 6;                  // 0..31
            int nn = idx & 63;                  // 0..63
            Bs[kk][nn] = B[(size_t)(kc + kk) * HF + n0 + nn];
        }
        __syncthreads();
        #pragma unroll
        for (int k = 0; k < KC; ++k) {
            float4 a = *(const float4*)&As[k][4 * ty];
            float4 b = *(const float4*)&Bs[k][4 * tx];
            acc[0][0] = fmaf(a.x, b.x, acc[0][0]); acc[0][1] = fmaf(a.x, b.y, acc[0][1]);
            acc[0][2] = fmaf(a.x, b.z, acc[0][2]); acc[0][3] = fmaf(a.x, b.w, acc[0][3]);
            acc[1][0] = fmaf(a.y, b.x, acc[1][0]); acc[1][1] = fmaf(a.y, b.y, acc[1][1]);
            acc[1][2] = fmaf(a.y, b.z, acc[1][2]); acc[1][3] = fmaf(a.y, b.w, acc[1][3]);
            acc[2][0] = fmaf(a.z, b.x, acc[2][0]); acc[2][1] = fmaf(a.z, b.y, acc[2][1]);
            acc[2][2] = fmaf(a.z, b.z, acc[2][2]); acc[2][3] = fmaf(a.z, b.w, acc[2][3]);
            acc[3][0] = fmaf(a.w, b.x, acc[3][0]); acc[3][1] = fmaf(a.w, b.y, acc[3][1]);
            acc[3][2] = fmaf(a.w, b.z, acc[3][2]); acc[3][3] = fmaf(a.w, b.w, acc[3][3]);
        }
        __syncthreads();
    }

    float4 bb = make_float4(0.f, 0.f, 0.f, 0.f);
    if (bias) bb = *(const float4*)&bias[n0 + 4 * tx];
    #pragma unroll
    for (int i = 0; i < 4; ++i) {
        int row = m0 + 4 * ty + i;
        if (row < M) {
            float4 v = make_float4(acc[i][0] + bb.x, acc[i][1] + bb.y,
                                   acc[i][2] + bb.z, acc[i][3] + bb.w);
            *(float4*)&C[(size_t)row * HF + n0 + 4 * tx] = v;
        }
    }
}

// ======================= attention scalars: as_[i]=hp[i].a_s, ad_[i]=hp[i].a_d ==========
__global__ __launch_bounds__(256) void k_alpha(const float* __restrict__ hp,
                                               const float* __restrict__ a_s,
                                               const float* __restrict__ a_d,
                                               float* __restrict__ as_, float* __restrict__ ad_,
                                               int n) {
    int wave = (blockIdx.x * 256 + threadIdx.x) >> 6;
    int lane = threadIdx.x & 63;
    if (wave >= n) return;
    float2 v  = ((const float2*)(hp + (size_t)wave * HF))[lane];
    float2 s2 = ((const float2*)a_s)[lane];
    float2 d2 = ((const float2*)a_d)[lane];
    float ps = v.x * s2.x + v.y * s2.y;
    float pd = v.x * d2.x + v.y * d2.y;
    for (int off = 32; off; off >>= 1) {
        ps += __shfl_xor(ps, off);
        pd += __shfl_xor(pd, off);
    }
    if (lane == 0) { as_[wave] = ps; ad_[wave] = pd; }
}

// ======================= per-dst softmax aggregation (one wave per node) ==========
__global__ __launch_bounds__(256) void k_agg(const int* __restrict__ rowptr,
                                             const int* __restrict__ colidx,
                                             const float* __restrict__ hp,
                                             const float* __restrict__ as_,
                                             const float* __restrict__ ad_,
                                             const float* __restrict__ bl,
                                             float* __restrict__ hout,
                                             int n, int relu) {
    int wave = (blockIdx.x * 256 + threadIdx.x) >> 6;
    int lane = threadIdx.x & 63;
    if (wave >= n) return;
    int beg = rowptr[wave], end = rowptr[wave + 1];
    float adi = ad_[wave];

    // pass 1a: max over incoming edges
    float m = -1e30f;
    for (int j = beg + lane; j < end; j += 64) {
        float e = as_[colidx[j]] + adi;
        e = e > 0.f ? e : NEG * e;
        m = fmaxf(m, e);
    }
    for (int off = 32; off; off >>= 1) m = fmaxf(m, __shfl_xor(m, off));

    // pass 1b: denom
    float ssum = 0.f;
    for (int j = beg + lane; j < end; j += 64) {
        float e = as_[colidx[j]] + adi;
        e = e > 0.f ? e : NEG * e;
        ssum += __expf(e - m);
    }
    for (int off = 32; off; off >>= 1) ssum += __shfl_xor(ssum, off);
    float inv = 1.f / ssum;

    // pass 2: weighted feature gather (2 dims per lane)
    float acc0 = 0.f, acc1 = 0.f;
    for (int j = beg; j < end; ++j) {
        int srcn = colidx[j];                   // wave-uniform broadcast
        float e = as_[srcn] + adi;
        e = e > 0.f ? e : NEG * e;
        float w = __expf(e - m) * inv;
        float2 v = ((const float2*)(hp + (size_t)srcn * HF))[lane];
        acc0 = fmaf(w, v.x, acc0);
        acc1 = fmaf(w, v.y, acc1);
    }
    float2 bb = ((const float2*)bl)[lane];
    acc0 += bb.x; acc1 += bb.y;
    if (relu) { acc0 = fmaxf(acc0, 0.f); acc1 = fmaxf(acc1, 0.f); }
    ((float2*)(hout + (size_t)wave * HF))[lane] = make_float2(acc0, acc1);
}

// ======================= pooling over sorted batch (parallel, atomic flush) ==========
__global__ void k_pool_zero(float* pooled) {
    pooled[blockIdx.x * HF + threadIdx.x] = 0.f;   // grid GCOUNT, 128 threads
}

// 128 threads (one per feature), each block owns PROWS consecutive rows.
// batch sorted -> a chunk spans few groups; accumulate in reg, flush on change.
#define PROWS 128
__global__ __launch_bounds__(128) void k_pool(const float* __restrict__ h,
                                              const int* __restrict__ batch,
                                              float* __restrict__ pooled, int n) {
    int r0 = blockIdx.x * PROWS;
    int r1 = min(r0 + PROWS, n);
    if (r0 >= r1) return;
    int t = threadIdx.x;
    int cur = batch[r0];
    float acc = 0.f;
    for (int i = r0; i < r1; ++i) {
        int b = batch[i];
        if (b != cur) {
            atomicAdd(&pooled[cur * HF + t], acc);
            acc = 0.f;
            cur = b;
        }
        acc += h[(size_t)i * HF + t];
    }
    atomicAdd(&pooled[cur * HF + t], acc);
}

__global__ void k_final(const float* __restrict__ pooled, const float* __restrict__ Wf,
                        const float* __restrict__ bf, float* __restrict__ out) {
    int g = blockIdx.x, o = threadIdx.x;   // 64 threads
    float acc = bf[o];
    #pragma unroll 8
    for (int k = 0; k < HF; ++k) acc = fmaf(pooled[g * HF + k], Wf[k * OUTF + o], acc);
    out[g * OUTF + o] = acc;
}

// ======================= launch =======================
extern "C" void kernel_launch(void* const* d_in, const int* in_sizes, int n_in,
                              void* d_out, int out_size, void* d_ws, size_t ws_size,
                              hipStream_t stream) {
    const float* x      = (const float*)d_in[0];
    const int*   edge   = (const int*)d_in[1];
    const int*   batch  = (const int*)d_in[2];
    const float* W0     = (const float*)d_in[3];
    const float* b0     = (const float*)d_in[4];
    const float* Wl     = (const float*)d_in[5];
    const float* a_src  = (const float*)d_in[6];
    const float* a_dst  = (const float*)d_in[7];
    const float* bl     = (const float*)d_in[8];
    const float* Wf     = (const float*)d_in[9];
    const float* bf     = (const float*)d_in[10];
    float* out = (float*)d_out;

    const int N  = in_sizes[2];
    const int E  = in_sizes[1] / 2;
    const int Et = E + N;
    const int L  = 3;

    // workspace layout
    char* ws = (char*)d_ws;
    size_t off = 0;
    auto alloc = [&](size_t bytes) { char* p = ws + off; off += (bytes + 255) & ~(size_t)255; return p; };
    float* h      = (float*)alloc((size_t)N * HF * 4);
    float* hp     = (float*)alloc((size_t)N * HF * 4);
    float* as_    = (float*)alloc((size_t)N * 4);
    float* ad_    = (float*)alloc((size_t)N * 4);
    int*   rowptr = (int*)alloc((size_t)(N + 1) * 4);
    int*   cur    = (int*)alloc((size_t)N * 4);
    int*   colidx = (int*)alloc((size_t)Et * 4);
    int*   bsums  = (int*)alloc(1024);
    float* pooled = (float*)alloc((size_t)GCOUNT * HF * 4);
    (void)ws_size; (void)n_in; (void)out_size;

    const int nb256  = (N + 255) / 256;          // 196
    const int eb256  = (E + 255) / 256;
    const int tb256  = (Et + 255) / 256;
    const int wb4    = (N + 3) / 4;              // wave-per-node kernels

    const int* esrc = edge;
    const int* edst = edge + E;

    // --- build dst-CSR (reused across all 3 layers) ---
    k_set_deg<<<nb256, 256, 0, stream>>>(rowptr, N);
    k_hist<<<eb256, 256, 0, stream>>>(edst, rowptr, E);
    k_scan_partial<<<nb256, 256, 0, stream>>>(rowptr, bsums, N);
    k_scan_block<<<1, 256, 0, stream>>>(bsums, nb256);
    k_scan_add<<<nb256, 256, 0, stream>>>(rowptr, bsums, N, Et);
    k_copy<<<nb256, 256, 0, stream>>>(rowptr, cur, N);
    k_fill<<<tb256, 256, 0, stream>>>(esrc, edst, cur, colidx, E, N);

    // --- h = x @ W0 + b0 ---
    dim3 ggrid((N + TM - 1) / TM, HF / TN);
    k_gemm<<<ggrid, 256, 0, stream>>>(x, W0, b0, h, N);

    // --- GAT layers ---
    for (int l = 0; l < L; ++l) {
        k_gemm<<<ggrid, 256, 0, stream>>>(h, Wl + (size_t)l * HF * HF, nullptr, hp, N);
        k_alpha<<<wb4, 256, 0, stream>>>(hp, a_src + l * HF, a_dst + l * HF, as_, ad_, N);
        k_agg<<<wb4, 256, 0, stream>>>(rowptr, colidx, hp, as_, ad_, bl + l * HF, h, N,
                                       (l < L - 1) ? 1 : 0);
    }

    // --- pooling + final linear ---
    k_pool_zero<<<GCOUNT, HF, 0, stream>>>(pooled);
    k_pool<<<(N + PROWS - 1) / PROWS, 128, 0, stream>>>(h, batch, pooled, N);
    k_final<<<GCOUNT, OUTF, 0, stream>>>(pooled, Wf, bf, out);
}

// Round 4
// 568.905 us; speedup vs baseline: 1.9344x; 1.2207x over previous
//
#include <hip/hip_runtime.h>
#include <hip/hip_bf16.h>
#include <math.h>

#define HF 128          // hidden / input feature dim
#define GCOUNT 64       // graphs in batch
#define OUTF 64         // final output features
#define NEG 0.2f        // leaky relu slope

// ======================= CSR build (dst-indexed) =======================
__global__ void k_set_deg(int* deg, int n) {
    int i = blockIdx.x * 256 + threadIdx.x;
    if (i < n) deg[i] = 1;  // self loop contributes 1 incoming edge
}

__global__ void k_hist(const int* __restrict__ edst, int* deg, int ne) {
    int i = blockIdx.x * 256 + threadIdx.x;
    if (i < ne) atomicAdd(&deg[edst[i]], 1);
}

// in-place exclusive scan, chunk of 256 per block; bsums[b] = chunk total
__global__ void k_scan_partial(int* data, int* bsums, int n) {
    __shared__ int s[256];
    int i = blockIdx.x * 256 + threadIdx.x;
    int v = (i < n) ? data[i] : 0;
    s[threadIdx.x] = v;
    __syncthreads();
    int acc = v;
    for (int off = 1; off < 256; off <<= 1) {
        int t = (threadIdx.x >= off) ? s[threadIdx.x - off] : 0;
        __syncthreads();
        acc += t;
        s[threadIdx.x] = acc;
        __syncthreads();
    }
    if (i < n) data[i] = acc - v;          // exclusive within chunk
    if (threadIdx.x == 255) bsums[blockIdx.x] = acc;
}

__global__ void k_scan_block(int* b, int nb) {
    __shared__ int s[256];
    int v = (threadIdx.x < nb) ? b[threadIdx.x] : 0;
    s[threadIdx.x] = v;
    __syncthreads();
    int acc = v;
    for (int off = 1; off < 256; off <<= 1) {
        int t = (threadIdx.x >= off) ? s[threadIdx.x - off] : 0;
        __syncthreads();
        acc += t;
        s[threadIdx.x] = acc;
        __syncthreads();
    }
    if (threadIdx.x < nb) b[threadIdx.x] = acc - v;  // exclusive block offsets
}

__global__ void k_scan_add(int* data, const int* __restrict__ bsums, int n, int total) {
    int i = blockIdx.x * 256 + threadIdx.x;
    if (i < n) data[i] += bsums[blockIdx.x];
    if (i == 0) data[n] = total;           // rowptr[N] = E + N (known)
}

__global__ void k_copy(const int* __restrict__ a, int* b, int n) {
    int i = blockIdx.x * 256 + threadIdx.x;
    if (i < n) b[i] = a[i];
}

__global__ void k_fill(const int* __restrict__ esrc, const int* __restrict__ edst,
                       int* cur, int* colidx, int ne, int n) {
    int t = blockIdx.x * 256 + threadIdx.x;
    if (t >= ne + n) return;
    int s, d;
    if (t < ne) { s = esrc[t]; d = edst[t]; }
    else        { s = t - ne; d = s; }     // self loop
    int pos = atomicAdd(&cur[d], 1);
    colidx[pos] = s;
}

// ======================= fp32 GEMM: C[M x 128] = A[M x 128] @ B[128 x 128] (+bias) ==========
#define TM 64
#define TN 64
#define KC 32
__global__ __launch_bounds__(256) void k_gemm(const float* __restrict__ A,
                                              const float* __restrict__ B,
                                              const float* __restrict__ bias,
                                              float* __restrict__ C, int M) {
    __shared__ float As[KC][TM + 4];   // transposed A tile: As[k][m], +4 pad keeps 16B align
    __shared__ float Bs[KC][TN];
    const int m0 = blockIdx.x * TM;
    const int n0 = blockIdx.y * TN;
    const int tid = threadIdx.x;
    const int tx = tid & 15, ty = tid >> 4;

    float acc[4][4] = {};

    for (int kc = 0; kc < HF; kc += KC) {
        #pragma unroll
        for (int i = 0; i < 8; ++i) {
            int idx = tid + i * 256;
            int mm = idx >> 5;                  // 0..63
            int kk = idx & 31;                  // 0..31
            int row = m0 + mm;
            As[kk][mm] = (row < M) ? A[(size_t)row * HF + kc + kk] : 0.f;
        }
        #pragma unroll
        for (int i = 0; i < 8; ++i) {
            int idx = tid + i * 256;
            int kk = idx >> 6;                  // 0..31
            int nn = idx & 63;                  // 0..63
            Bs[kk][nn] = B[(size_t)(kc + kk) * HF + n0 + nn];
        }
        __syncthreads();
        #pragma unroll
        for (int k = 0; k < KC; ++k) {
            float4 a = *(const float4*)&As[k][4 * ty];
            float4 b = *(const float4*)&Bs[k][4 * tx];
            acc[0][0] = fmaf(a.x, b.x, acc[0][0]); acc[0][1] = fmaf(a.x, b.y, acc[0][1]);
            acc[0][2] = fmaf(a.x, b.z, acc[0][2]); acc[0][3] = fmaf(a.x, b.w, acc[0][3]);
            acc[1][0] = fmaf(a.y, b.x, acc[1][0]); acc[1][1] = fmaf(a.y, b.y, acc[1][1]);
            acc[1][2] = fmaf(a.y, b.z, acc[1][2]); acc[1][3] = fmaf(a.y, b.w, acc[1][3]);
            acc[2][0] = fmaf(a.z, b.x, acc[2][0]); acc[2][1] = fmaf(a.z, b.y, acc[2][1]);
            acc[2][2] = fmaf(a.z, b.z, acc[2][2]); acc[2][3] = fmaf(a.z, b.w, acc[2][3]);
            acc[3][0] = fmaf(a.w, b.x, acc[3][0]); acc[3][1] = fmaf(a.w, b.y, acc[3][1]);
            acc[3][2] = fmaf(a.w, b.z, acc[3][2]); acc[3][3] = fmaf(a.w, b.w, acc[3][3]);
        }
        __syncthreads();
    }

    float4 bb = make_float4(0.f, 0.f, 0.f, 0.f);
    if (bias) bb = *(const float4*)&bias[n0 + 4 * tx];
    #pragma unroll
    for (int i = 0; i < 4; ++i) {
        int row = m0 + 4 * ty + i;
        if (row < M) {
            float4 v = make_float4(acc[i][0] + bb.x, acc[i][1] + bb.y,
                                   acc[i][2] + bb.z, acc[i][3] + bb.w);
            *(float4*)&C[(size_t)row * HF + n0 + 4 * tx] = v;
        }
    }
}

// ======================= attention scalars: as_[i]=hp[i].a_s, ad_[i]=hp[i].a_d ==========
__global__ __launch_bounds__(256) void k_alpha(const float* __restrict__ hp,
                                               const float* __restrict__ a_s,
                                               const float* __restrict__ a_d,
                                               float* __restrict__ as_, float* __restrict__ ad_,
                                               int n) {
    int wave = (blockIdx.x * 256 + threadIdx.x) >> 6;
    int lane = threadIdx.x & 63;
    if (wave >= n) return;
    float2 v  = ((const float2*)(hp + (size_t)wave * HF))[lane];
    float2 s2 = ((const float2*)a_s)[lane];
    float2 d2 = ((const float2*)a_d)[lane];
    float ps = v.x * s2.x + v.y * s2.y;
    float pd = v.x * d2.x + v.y * d2.y;
    for (int off = 32; off; off >>= 1) {
        ps += __shfl_xor(ps, off);
        pd += __shfl_xor(pd, off);
    }
    if (lane == 0) { as_[wave] = ps; ad_[wave] = pd; }
}

// ======================= per-dst softmax aggregation (one wave per node) ==========
// deg <= 64 fast path: colidx + as_ gathered ONCE into registers; exp computed once;
// pass 2 broadcasts (src, w) via shuffle and unrolls x4 for memory-level parallelism.
__global__ __launch_bounds__(256) void k_agg(const int* __restrict__ rowptr,
                                             const int* __restrict__ colidx,
                                             const float* __restrict__ hp,
                                             const float* __restrict__ as_,
                                             const float* __restrict__ ad_,
                                             const float* __restrict__ bl,
                                             float* __restrict__ hout,
                                             int n, int relu) {
    int wave = (blockIdx.x * 256 + threadIdx.x) >> 6;
    int lane = threadIdx.x & 63;
    if (wave >= n) return;
    int beg = rowptr[wave], end = rowptr[wave + 1];
    int deg = end - beg;
    float adi = ad_[wave];

    // lane-owned edge (first 64 edges)
    int  srcl = (lane < deg) ? colidx[beg + lane] : 0;
    float el = -1e30f;
    if (lane < deg) {
        float e = as_[srcl] + adi;
        el = e > 0.f ? e : NEG * e;
    }

    // max (incl. rare >64 tail)
    float m = el;
    for (int jj = beg + 64 + lane; jj < end; jj += 64) {
        float e = as_[colidx[jj]] + adi;
        e = e > 0.f ? e : NEG * e;
        m = fmaxf(m, e);
    }
    #pragma unroll
    for (int off = 32; off; off >>= 1) m = fmaxf(m, __shfl_xor(m, off));

    // denom
    float ex = (lane < deg) ? __expf(el - m) : 0.f;
    float ssum = ex;
    for (int jj = beg + 64 + lane; jj < end; jj += 64) {
        float e = as_[colidx[jj]] + adi;
        e = e > 0.f ? e : NEG * e;
        ssum += __expf(e - m);
    }
    #pragma unroll
    for (int off = 32; off; off >>= 1) ssum += __shfl_xor(ssum, off);
    float inv = 1.f / ssum;
    float wl = ex * inv;        // this lane's edge weight

    // pass 2: weighted feature gather, broadcast (src, w) from owning lane
    float acc0 = 0.f, acc1 = 0.f;
    int cnt = deg < 64 ? deg : 64;
    int t = 0;
    for (; t + 4 <= cnt; t += 4) {
        int   s0 = __shfl(srcl, t    ), s1 = __shfl(srcl, t + 1);
        int   s2 = __shfl(srcl, t + 2), s3 = __shfl(srcl, t + 3);
        float w0 = __shfl(wl,   t    ), w1 = __shfl(wl,   t + 1);
        float w2 = __shfl(wl,   t + 2), w3 = __shfl(wl,   t + 3);
        float2 v0 = ((const float2*)(hp + (size_t)s0 * HF))[lane];
        float2 v1 = ((const float2*)(hp + (size_t)s1 * HF))[lane];
        float2 v2 = ((const float2*)(hp + (size_t)s2 * HF))[lane];
        float2 v3 = ((const float2*)(hp + (size_t)s3 * HF))[lane];
        acc0 = fmaf(w0, v0.x, acc0); acc1 = fmaf(w0, v0.y, acc1);
        acc0 = fmaf(w1, v1.x, acc0); acc1 = fmaf(w1, v1.y, acc1);
        acc0 = fmaf(w2, v2.x, acc0); acc1 = fmaf(w2, v2.y, acc1);
        acc0 = fmaf(w3, v3.x, acc0); acc1 = fmaf(w3, v3.y, acc1);
    }
    for (; t < cnt; ++t) {
        int   s0 = __shfl(srcl, t);
        float w0 = __shfl(wl,   t);
        float2 v0 = ((const float2*)(hp + (size_t)s0 * HF))[lane];
        acc0 = fmaf(w0, v0.x, acc0); acc1 = fmaf(w0, v0.y, acc1);
    }
    // rare >64 tail: recompute weight serially
    for (int jj = beg + 64; jj < end; ++jj) {
        int srcn = colidx[jj];
        float e = as_[srcn] + adi;
        e = e > 0.f ? e : NEG * e;
        float w = __expf(e - m) * inv;
        float2 v = ((const float2*)(hp + (size_t)srcn * HF))[lane];
        acc0 = fmaf(w, v.x, acc0); acc1 = fmaf(w, v.y, acc1);
    }

    float2 bb = ((const float2*)bl)[lane];
    acc0 += bb.x; acc1 += bb.y;
    if (relu) { acc0 = fmaxf(acc0, 0.f); acc1 = fmaxf(acc1, 0.f); }
    ((float2*)(hout + (size_t)wave * HF))[lane] = make_float2(acc0, acc1);
}

// ======================= pooling over sorted batch (parallel, atomic flush) ==========
__global__ void k_pool_zero(float* pooled) {
    pooled[blockIdx.x * HF + threadIdx.x] = 0.f;   // grid GCOUNT, 128 threads
}

// 128 threads (one per feature), each block owns PROWS consecutive rows.
// batch sorted -> a chunk spans few groups; accumulate in reg, flush on change.
#define PROWS 128
__global__ __launch_bounds__(128) void k_pool(const float* __restrict__ h,
                                              const int* __restrict__ batch,
                                              float* __restrict__ pooled, int n) {
    int r0 = blockIdx.x * PROWS;
    int r1 = min(r0 + PROWS, n);
    if (r0 >= r1) return;
    int t = threadIdx.x;
    int cur = batch[r0];
    float acc = 0.f;
    for (int i = r0; i < r1; ++i) {
        int b = batch[i];
        if (b != cur) {
            atomicAdd(&pooled[cur * HF + t], acc);
            acc = 0.f;
            cur = b;
        }
        acc += h[(size_t)i * HF + t];
    }
    atomicAdd(&pooled[cur * HF + t], acc);
}

__global__ void k_final(const float* __restrict__ pooled, const float* __restrict__ Wf,
                        const float* __restrict__ bf, float* __restrict__ out) {
    int g = blockIdx.x, o = threadIdx.x;   // 64 threads
    float acc = bf[o];
    #pragma unroll 8
    for (int k = 0; k < HF; ++k) acc = fmaf(pooled[g * HF + k], Wf[k * OUTF + o], acc);
    out[g * OUTF + o] = acc;
}

// ======================= launch =======================
extern "C" void kernel_launch(void* const* d_in, const int* in_sizes, int n_in,
                              void* d_out, int out_size, void* d_ws, size_t ws_size,
                              hipStream_t stream) {
    const float* x      = (const float*)d_in[0];
    const int*   edge   = (const int*)d_in[1];
    const int*   batch  = (const int*)d_in[2];
    const float* W0     = (const float*)d_in[3];
    const float* b0     = (const float*)d_in[4];
    const float* Wl     = (const float*)d_in[5];
    const float* a_src  = (const float*)d_in[6];
    const float* a_dst  = (const float*)d_in[7];
    const float* bl     = (const float*)d_in[8];
    const float* Wf     = (const float*)d_in[9];
    const float* bf     = (const float*)d_in[10];
    float* out = (float*)d_out;

    const int N  = in_sizes[2];
    const int E  = in_sizes[1] / 2;
    const int Et = E + N;
    const int L  = 3;

    // workspace layout
    char* ws = (char*)d_ws;
    size_t off = 0;
    auto alloc = [&](size_t bytes) { char* p = ws + off; off += (bytes + 255) & ~(size_t)255; return p; };
    float* h      = (float*)alloc((size_t)N * HF * 4);
    float* hp     = (float*)alloc((size_t)N * HF * 4);
    float* as_    = (float*)alloc((size_t)N * 4);
    float* ad_    = (float*)alloc((size_t)N * 4);
    int*   rowptr = (int*)alloc((size_t)(N + 1) * 4);
    int*   cur    = (int*)alloc((size_t)N * 4);
    int*   colidx = (int*)alloc((size_t)Et * 4);
    int*   bsums  = (int*)alloc(1024);
    float* pooled = (float*)alloc((size_t)GCOUNT * HF * 4);
    (void)ws_size; (void)n_in; (void)out_size;

    const int nb256  = (N + 255) / 256;          // 196
    const int eb256  = (E + 255) / 256;
    const int tb256  = (Et + 255) / 256;
    const int wb4    = (N + 3) / 4;              // wave-per-node kernels

    const int* esrc = edge;
    const int* edst = edge + E;

    // --- build dst-CSR (reused across all 3 layers) ---
    k_set_deg<<<nb256, 256, 0, stream>>>(rowptr, N);
    k_hist<<<eb256, 256, 0, stream>>>(edst, rowptr, E);
    k_scan_partial<<<nb256, 256, 0, stream>>>(rowptr, bsums, N);
    k_scan_block<<<1, 256, 0, stream>>>(bsums, nb256);
    k_scan_add<<<nb256, 256, 0, stream>>>(rowptr, bsums, N, Et);
    k_copy<<<nb256, 256, 0, stream>>>(rowptr, cur, N);
    k_fill<<<tb256, 256, 0, stream>>>(esrc, edst, cur, colidx, E, N);

    // --- h = x @ W0 + b0 ---
    dim3 ggrid((N + TM - 1) / TM, HF / TN);
    k_gemm<<<ggrid, 256, 0, stream>>>(x, W0, b0, h, N);

    // --- GAT layers ---
    for (int l = 0; l < L; ++l) {
        k_gemm<<<ggrid, 256, 0, stream>>>(h, Wl + (size_t)l * HF * HF, nullptr, hp, N);
        k_alpha<<<wb4, 256, 0, stream>>>(hp, a_src + l * HF, a_dst + l * HF, as_, ad_, N);
        k_agg<<<wb4, 256, 0, stream>>>(rowptr, colidx, hp, as_, ad_, bl + l * HF, h, N,
                                       (l < L - 1) ? 1 : 0);
    }

    // --- pooling + final linear ---
    k_pool_zero<<<GCOUNT, HF, 0, stream>>>(pooled);
    k_pool<<<(N + PROWS - 1) / PROWS, 128, 0, stream>>>(h, batch, pooled, N);
    k_final<<<GCOUNT, OUTF, 0, stream>>>(pooled, Wf, bf, out);
}

// Round 5
// 440.612 us; speedup vs baseline: 2.4977x; 1.2912x over previous
//
#include <hip/hip_runtime.h>
#include <hip/hip_bf16.h>
#include <math.h>

#define HF 128          // hidden / input feature dim
#define GCOUNT 64       // graphs in batch
#define OUTF 64         // final output features
#define NEG 0.2f        // leaky relu slope

typedef unsigned short u16;
typedef unsigned int   u32;
typedef short bf16x8 __attribute__((ext_vector_type(8)));
typedef float f32x4  __attribute__((ext_vector_type(4)));

// fp32 -> bf16 (RNE) bit trick
__device__ __forceinline__ u16 f2b(float f) {
    u32 u = __builtin_bit_cast(u32, f);
    u32 r = (u + 0x7FFFu + ((u >> 16) & 1u)) >> 16;
    return (u16)r;
}
// unpack packed pair (little-endian: lo = even col)
__device__ __forceinline__ float blo(u32 u) { return __builtin_bit_cast(float, u << 16); }
__device__ __forceinline__ float bhi(u32 u) { return __builtin_bit_cast(float, u & 0xFFFF0000u); }

// ======================= CSR build (dst-indexed) =======================
__global__ void k_set_deg(int* deg, int n) {
    int i = blockIdx.x * 256 + threadIdx.x;
    if (i < n) deg[i] = 1;  // self loop contributes 1 incoming edge
}

__global__ void k_hist(const int* __restrict__ edst, int* deg, int ne) {
    int i = blockIdx.x * 256 + threadIdx.x;
    if (i < ne) atomicAdd(&deg[edst[i]], 1);
}

__global__ void k_scan_partial(int* data, int* bsums, int n) {
    __shared__ int s[256];
    int i = blockIdx.x * 256 + threadIdx.x;
    int v = (i < n) ? data[i] : 0;
    s[threadIdx.x] = v;
    __syncthreads();
    int acc = v;
    for (int off = 1; off < 256; off <<= 1) {
        int t = (threadIdx.x >= off) ? s[threadIdx.x - off] : 0;
        __syncthreads();
        acc += t;
        s[threadIdx.x] = acc;
        __syncthreads();
    }
    if (i < n) data[i] = acc - v;
    if (threadIdx.x == 255) bsums[blockIdx.x] = acc;
}

__global__ void k_scan_block(int* b, int nb) {
    __shared__ int s[256];
    int v = (threadIdx.x < nb) ? b[threadIdx.x] : 0;
    s[threadIdx.x] = v;
    __syncthreads();
    int acc = v;
    for (int off = 1; off < 256; off <<= 1) {
        int t = (threadIdx.x >= off) ? s[threadIdx.x - off] : 0;
        __syncthreads();
        acc += t;
        s[threadIdx.x] = acc;
        __syncthreads();
    }
    if (threadIdx.x < nb) b[threadIdx.x] = acc - v;
}

__global__ void k_scan_add(int* data, const int* __restrict__ bsums, int n, int total) {
    int i = blockIdx.x * 256 + threadIdx.x;
    if (i < n) data[i] += bsums[blockIdx.x];
    if (i == 0) data[n] = total;
}

__global__ void k_copy(const int* __restrict__ a, int* b, int n) {
    int i = blockIdx.x * 256 + threadIdx.x;
    if (i < n) b[i] = a[i];
}

__global__ void k_fill(const int* __restrict__ esrc, const int* __restrict__ edst,
                       int* cur, int* colidx, int ne, int n) {
    int t = blockIdx.x * 256 + threadIdx.x;
    if (t >= ne + n) return;
    int s, d;
    if (t < ne) { s = esrc[t]; d = edst[t]; }
    else        { s = t - ne; d = s; }
    int pos = atomicAdd(&cur[d], 1);
    colidx[pos] = s;
}

// ======================= bf16 conversions / packing ==========
__global__ void k_cvt(const float* __restrict__ X, u16* __restrict__ Xb, int n4) {
    int i = blockIdx.x * 256 + threadIdx.x;
    if (i >= n4) return;
    float4 v = ((const float4*)X)[i];
    ushort4 o;
    o.x = f2b(v.x); o.y = f2b(v.y); o.z = f2b(v.z); o.w = f2b(v.w);
    ((ushort4*)Xb)[i] = o;
}

// pack W[128][128] fp32 row-major (W[k][n]) into MFMA B-frag order:
// P[(t*4+kc)*64+lane][j] = bf16(W[kc*32+quad*8+j][16t+(lane&15)])
__global__ void k_pack(const float* __restrict__ W, u16* __restrict__ P) {
    int i = blockIdx.x * 256 + threadIdx.x;   // 0..2047
    if (i >= 2048) return;
    int lane = i & 63, kc = (i >> 6) & 3, t = i >> 8;
    int quad = lane >> 4, col = 16 * t + (lane & 15);
    #pragma unroll
    for (int j = 0; j < 8; ++j) {
        int k = kc * 32 + quad * 8 + j;
        P[(size_t)i * 8 + j] = f2b(W[k * HF + col]);
    }
}

// ======================= MFMA GEMM: C[M x 128](bf16) = A[M x 128](bf16) @ Wpack (+bias) ==========
// block = 256 (4 waves); wave w owns rows m0+16w .. +15, all 128 cols (8 n-tiles).
// A-frag: lane holds A[m0+ (lane&15)][kc*32 + quad*8 + j]  (16B contiguous load)
// C/D layout: col = lane&15 (in tile), row = quad*4 + reg
__global__ __launch_bounds__(256) void k_gemm_mfma(const u16* __restrict__ A,
                                                   const u16* __restrict__ Bp,
                                                   const float* __restrict__ bias,
                                                   u16* __restrict__ C, int M) {
    int lane = threadIdx.x & 63;
    int wave = threadIdx.x >> 6;
    int quad = lane >> 4, l16 = lane & 15;
    int m0 = blockIdx.x * 64 + wave * 16;
    int arow = m0 + l16;
    bool aval = arow < M;
    const bf16x8* Av = (const bf16x8*)(A + (size_t)arow * HF);
    const bf16x8* Bv = (const bf16x8*)Bp;
    f32x4 acc[8] = {};

    #pragma unroll
    for (int kc = 0; kc < 4; ++kc) {
        bf16x8 a = {};
        if (aval) a = Av[kc * 4 + quad];
        #pragma unroll
        for (int t = 0; t < 8; ++t)
            acc[t] = __builtin_amdgcn_mfma_f32_16x16x32_bf16(a, Bv[t * 256 + kc * 64 + lane],
                                                             acc[t], 0, 0, 0);
    }

    int orow0 = m0 + quad * 4;
    #pragma unroll
    for (int t = 0; t < 8; ++t) {
        float b4 = bias ? bias[t * 16 + l16] : 0.f;
        #pragma unroll
        for (int r = 0; r < 4; ++r) {
            int orow = orow0 + r;
            if (orow < M) C[(size_t)orow * HF + t * 16 + l16] = f2b(acc[t][r] + b4);
        }
    }
}

// ======================= attention scalars from bf16 hp ==========
__global__ __launch_bounds__(256) void k_alpha(const u16* __restrict__ hpb,
                                               const float* __restrict__ a_s,
                                               const float* __restrict__ a_d,
                                               float* __restrict__ as_, float* __restrict__ ad_,
                                               int n) {
    int wave = (blockIdx.x * 256 + threadIdx.x) >> 6;
    int lane = threadIdx.x & 63;
    if (wave >= n) return;
    u32 u = ((const u32*)(hpb + (size_t)wave * HF))[lane];
    float x0 = blo(u), x1 = bhi(u);
    float2 s2 = ((const float2*)a_s)[lane];
    float2 d2 = ((const float2*)a_d)[lane];
    float ps = x0 * s2.x + x1 * s2.y;
    float pd = x0 * d2.x + x1 * d2.y;
    for (int off = 32; off; off >>= 1) {
        ps += __shfl_xor(ps, off);
        pd += __shfl_xor(pd, off);
    }
    if (lane == 0) { as_[wave] = ps; ad_[wave] = pd; }
}

// ======================= per-dst softmax aggregation (bf16 gather) ==========
__global__ __launch_bounds__(256) void k_agg(const int* __restrict__ rowptr,
                                             const int* __restrict__ colidx,
                                             const u16* __restrict__ hpb,
                                             const float* __restrict__ as_,
                                             const float* __restrict__ ad_,
                                             const float* __restrict__ bl,
                                             u16* __restrict__ hout,
                                             int n, int relu) {
    int wave = (blockIdx.x * 256 + threadIdx.x) >> 6;
    int lane = threadIdx.x & 63;
    if (wave >= n) return;
    int beg = rowptr[wave], end = rowptr[wave + 1];
    int deg = end - beg;
    float adi = ad_[wave];

    int  srcl = (lane < deg) ? colidx[beg + lane] : 0;
    float el = -1e30f;
    if (lane < deg) {
        float e = as_[srcl] + adi;
        el = e > 0.f ? e : NEG * e;
    }

    float m = el;
    for (int jj = beg + 64 + lane; jj < end; jj += 64) {
        float e = as_[colidx[jj]] + adi;
        e = e > 0.f ? e : NEG * e;
        m = fmaxf(m, e);
    }
    #pragma unroll
    for (int off = 32; off; off >>= 1) m = fmaxf(m, __shfl_xor(m, off));

    float ex = (lane < deg) ? __expf(el - m) : 0.f;
    float ssum = ex;
    for (int jj = beg + 64 + lane; jj < end; jj += 64) {
        float e = as_[colidx[jj]] + adi;
        e = e > 0.f ? e : NEG * e;
        ssum += __expf(e - m);
    }
    #pragma unroll
    for (int off = 32; off; off >>= 1) ssum += __shfl_xor(ssum, off);
    float inv = 1.f / ssum;
    float wl = ex * inv;

    float acc0 = 0.f, acc1 = 0.f;
    int cnt = deg < 64 ? deg : 64;
    int t = 0;
    for (; t + 4 <= cnt; t += 4) {
        int   s0 = __shfl(srcl, t    ), s1 = __shfl(srcl, t + 1);
        int   s2 = __shfl(srcl, t + 2), s3 = __shfl(srcl, t + 3);
        float w0 = __shfl(wl,   t    ), w1 = __shfl(wl,   t + 1);
        float w2 = __shfl(wl,   t + 2), w3 = __shfl(wl,   t + 3);
        u32 v0 = ((const u32*)(hpb + (size_t)s0 * HF))[lane];
        u32 v1 = ((const u32*)(hpb + (size_t)s1 * HF))[lane];
        u32 v2 = ((const u32*)(hpb + (size_t)s2 * HF))[lane];
        u32 v3 = ((const u32*)(hpb + (size_t)s3 * HF))[lane];
        acc0 = fmaf(w0, blo(v0), acc0); acc1 = fmaf(w0, bhi(v0), acc1);
        acc0 = fmaf(w1, blo(v1), acc0); acc1 = fmaf(w1, bhi(v1), acc1);
        acc0 = fmaf(w2, blo(v2), acc0); acc1 = fmaf(w2, bhi(v2), acc1);
        acc0 = fmaf(w3, blo(v3), acc0); acc1 = fmaf(w3, bhi(v3), acc1);
    }
    for (; t < cnt; ++t) {
        int   s0 = __shfl(srcl, t);
        float w0 = __shfl(wl,   t);
        u32 v0 = ((const u32*)(hpb + (size_t)s0 * HF))[lane];
        acc0 = fmaf(w0, blo(v0), acc0); acc1 = fmaf(w0, bhi(v0), acc1);
    }
    for (int jj = beg + 64; jj < end; ++jj) {   // rare deg>64 tail
        int srcn = colidx[jj];
        float e = as_[srcn] + adi;
        e = e > 0.f ? e : NEG * e;
        float w = __expf(e - m) * inv;
        u32 v = ((const u32*)(hpb + (size_t)srcn * HF))[lane];
        acc0 = fmaf(w, blo(v), acc0); acc1 = fmaf(w, bhi(v), acc1);
    }

    float2 bb = ((const float2*)bl)[lane];
    acc0 += bb.x; acc1 += bb.y;
    if (relu) { acc0 = fmaxf(acc0, 0.f); acc1 = fmaxf(acc1, 0.f); }
    u32 o = ((u32)f2b(acc1) << 16) | (u32)f2b(acc0);
    ((u32*)(hout + (size_t)wave * HF))[lane] = o;
}

// ======================= pooling over sorted batch (bf16 h, fp32 accum) ==========
__global__ void k_pool_zero(float* pooled) {
    pooled[blockIdx.x * HF + threadIdx.x] = 0.f;
}

#define PROWS 128
__global__ __launch_bounds__(128) void k_pool(const u16* __restrict__ hb,
                                              const int* __restrict__ batch,
                                              float* __restrict__ pooled, int n) {
    int r0 = blockIdx.x * PROWS;
    int r1 = min(r0 + PROWS, n);
    if (r0 >= r1) return;
    int t = threadIdx.x;
    int cur = batch[r0];
    float acc = 0.f;
    for (int i = r0; i < r1; ++i) {
        int b = batch[i];
        if (b != cur) {
            atomicAdd(&pooled[cur * HF + t], acc);
            acc = 0.f;
            cur = b;
        }
        acc += __builtin_bit_cast(float, (u32)hb[(size_t)i * HF + t] << 16);
    }
    atomicAdd(&pooled[cur * HF + t], acc);
}

__global__ void k_final(const float* __restrict__ pooled, const float* __restrict__ Wf,
                        const float* __restrict__ bf, float* __restrict__ out) {
    int g = blockIdx.x, o = threadIdx.x;   // 64 threads
    float acc = bf[o];
    #pragma unroll 8
    for (int k = 0; k < HF; ++k) acc = fmaf(pooled[g * HF + k], Wf[k * OUTF + o], acc);
    out[g * OUTF + o] = acc;
}

// ======================= launch =======================
extern "C" void kernel_launch(void* const* d_in, const int* in_sizes, int n_in,
                              void* d_out, int out_size, void* d_ws, size_t ws_size,
                              hipStream_t stream) {
    const float* x      = (const float*)d_in[0];
    const int*   edge   = (const int*)d_in[1];
    const int*   batch  = (const int*)d_in[2];
    const float* W0     = (const float*)d_in[3];
    const float* b0     = (const float*)d_in[4];
    const float* Wl     = (const float*)d_in[5];
    const float* a_src  = (const float*)d_in[6];
    const float* a_dst  = (const float*)d_in[7];
    const float* bl     = (const float*)d_in[8];
    const float* Wf     = (const float*)d_in[9];
    const float* bf     = (const float*)d_in[10];
    float* out = (float*)d_out;

    const int N  = in_sizes[2];
    const int E  = in_sizes[1] / 2;
    const int Et = E + N;
    const int L  = 3;

    char* ws = (char*)d_ws;
    size_t off = 0;
    auto alloc = [&](size_t bytes) { char* p = ws + off; off += (bytes + 255) & ~(size_t)255; return p; };
    u16*   xb     = (u16*)alloc((size_t)N * HF * 2);
    u16*   hb     = (u16*)alloc((size_t)N * HF * 2);
    u16*   hpb    = (u16*)alloc((size_t)N * HF * 2);
    u16*   Wp     = (u16*)alloc((size_t)4 * HF * HF * 2);   // W0 + 3 layers, packed
    float* as_    = (float*)alloc((size_t)N * 4);
    float* ad_    = (float*)alloc((size_t)N * 4);
    int*   rowptr = (int*)alloc((size_t)(N + 1) * 4);
    int*   cur    = (int*)alloc((size_t)N * 4);
    int*   colidx = (int*)alloc((size_t)Et * 4);
    int*   bsums  = (int*)alloc(1024);
    float* pooled = (float*)alloc((size_t)GCOUNT * HF * 4);
    (void)ws_size; (void)n_in; (void)out_size;

    const int nb256 = (N + 255) / 256;
    const int eb256 = (E + 255) / 256;
    const int tb256 = (Et + 255) / 256;
    const int wb4   = (N + 3) / 4;
    const int gemmb = (N + 63) / 64;

    const int* esrc = edge;
    const int* edst = edge + E;

    // --- pack weights + convert x to bf16 ---
    k_pack<<<8, 256, 0, stream>>>(W0, Wp);
    for (int l = 0; l < L; ++l)
        k_pack<<<8, 256, 0, stream>>>(Wl + (size_t)l * HF * HF, Wp + (size_t)(l + 1) * HF * HF);
    k_cvt<<<(N * HF / 4 + 255) / 256, 256, 0, stream>>>(x, xb, N * HF / 4);

    // --- build dst-CSR (reused across all 3 layers) ---
    k_set_deg<<<nb256, 256, 0, stream>>>(rowptr, N);
    k_hist<<<eb256, 256, 0, stream>>>(edst, rowptr, E);
    k_scan_partial<<<nb256, 256, 0, stream>>>(rowptr, bsums, N);
    k_scan_block<<<1, 256, 0, stream>>>(bsums, nb256);
    k_scan_add<<<nb256, 256, 0, stream>>>(rowptr, bsums, N, Et);
    k_copy<<<nb256, 256, 0, stream>>>(rowptr, cur, N);
    k_fill<<<tb256, 256, 0, stream>>>(esrc, edst, cur, colidx, E, N);

    // --- h = x @ W0 + b0 ---
    k_gemm_mfma<<<gemmb, 256, 0, stream>>>(xb, Wp, b0, hb, N);

    // --- GAT layers ---
    for (int l = 0; l < L; ++l) {
        k_gemm_mfma<<<gemmb, 256, 0, stream>>>(hb, Wp + (size_t)(l + 1) * HF * HF, nullptr, hpb, N);
        k_alpha<<<wb4, 256, 0, stream>>>(hpb, a_src + l * HF, a_dst + l * HF, as_, ad_, N);
        k_agg<<<wb4, 256, 0, stream>>>(rowptr, colidx, hpb, as_, ad_, bl + l * HF, hb, N,
                                       (l < L - 1) ? 1 : 0);
    }

    // --- pooling + final linear ---
    k_pool_zero<<<GCOUNT, HF, 0, stream>>>(pooled);
    k_pool<<<(N + PROWS - 1) / PROWS, 128, 0, stream>>>(hb, batch, pooled, N);
    k_final<<<GCOUNT, OUTF, 0, stream>>>(pooled, Wf, bf, out);
}

// Round 6
// 358.608 us; speedup vs baseline: 3.0688x; 1.2287x over previous
//
#include <hip/hip_runtime.h>
#include <hip/hip_bf16.h>
#include <math.h>

#define HF 128          // hidden / input feature dim
#define GCOUNT 64       // graphs in batch
#define OUTF 64         // final output features
#define NEG 0.2f        // leaky relu slope
#define CH 2048         // edges per partition block

typedef unsigned short u16;
typedef unsigned int   u32;
typedef short bf16x8 __attribute__((ext_vector_type(8)));
typedef float f32x4  __attribute__((ext_vector_type(4)));

// fp32 -> bf16 (RNE) bit trick
__device__ __forceinline__ u16 f2b(float f) {
    u32 u = __builtin_bit_cast(u32, f);
    u32 r = (u + 0x7FFFu + ((u >> 16) & 1u)) >> 16;
    return (u16)r;
}
__device__ __forceinline__ float blo(u32 u) { return __builtin_bit_cast(float, u << 16); }
__device__ __forceinline__ float bhi(u32 u) { return __builtin_bit_cast(float, u & 0xFFFF0000u); }

// ======================= bucketed CSR build =======================
// bucket = dst >> 8 (nodes 256-aligned). NB = ceil(N/256) <= 256.

__global__ void k_zero256(int* p) { p[threadIdx.x] = 0; }

__global__ __launch_bounds__(256) void k_bhist(const int* __restrict__ edst,
                                               int* __restrict__ bucketCnt, int ne, int ntot) {
    __shared__ int cnt[256];
    cnt[threadIdx.x] = 0;
    __syncthreads();
    int t0 = blockIdx.x * CH, t1 = min(t0 + CH, ntot);
    for (int t = t0 + threadIdx.x; t < t1; t += 256) {
        int d = (t < ne) ? edst[t] : t - ne;     // tail = self loops
        atomicAdd(&cnt[d >> 8], 1);
    }
    __syncthreads();
    int c = cnt[threadIdx.x];
    if (c) atomicAdd(&bucketCnt[threadIdx.x], c);
}

// single block: exclusive scan of bucketCnt -> bucketOff, init bucketCur, rowptr[N]=ntot
__global__ void k_bscan(const int* __restrict__ bucketCnt, int* bucketOff, int* bucketCur,
                        int* rowptr, int nb, int ntot, int n) {
    __shared__ int s[256];
    int tid = threadIdx.x;
    int v = (tid < nb) ? bucketCnt[tid] : 0;
    s[tid] = v;
    __syncthreads();
    int acc = v;
    for (int off = 1; off < 256; off <<= 1) {
        int t = (tid >= off) ? s[tid - off] : 0;
        __syncthreads();
        acc += t;
        s[tid] = acc;
        __syncthreads();
    }
    int excl = acc - v;
    if (tid < nb) { bucketOff[tid] = excl; bucketCur[tid] = excl; }
    if (tid == 0) { bucketOff[nb] = ntot; rowptr[n] = ntot; }
}

// partition edges into bucket regions; chunked reservation -> semi-coalesced writes
__global__ __launch_bounds__(256) void k_bpart(const int* __restrict__ esrc,
                                               const int* __restrict__ edst,
                                               int* __restrict__ bucketCur,
                                               int2* __restrict__ epart, int ne, int ntot) {
    __shared__ int cnt[256];
    __shared__ int base[256];
    int t0 = blockIdx.x * CH, t1 = min(t0 + CH, ntot);
    cnt[threadIdx.x] = 0;
    __syncthreads();
    for (int t = t0 + threadIdx.x; t < t1; t += 256) {
        int d = (t < ne) ? edst[t] : t - ne;
        atomicAdd(&cnt[d >> 8], 1);
    }
    __syncthreads();
    int c = cnt[threadIdx.x];
    base[threadIdx.x] = c ? atomicAdd(&bucketCur[threadIdx.x], c) : 0;
    cnt[threadIdx.x] = 0;
    __syncthreads();
    for (int t = t0 + threadIdx.x; t < t1; t += 256) {
        int s, d;
        if (t < ne) { s = esrc[t]; d = edst[t]; }
        else        { s = t - ne; d = s; }
        int b = d >> 8;
        int pos = base[b] + atomicAdd(&cnt[b], 1);
        epart[pos] = make_int2(s, d);
    }
}

// one block per bucket: local degree hist + scan -> rowptr + contiguous colidx scatter
__global__ __launch_bounds__(256) void k_bcsr(const int2* __restrict__ epart,
                                              const int* __restrict__ bucketOff,
                                              int* __restrict__ rowptr,
                                              int* __restrict__ colidx, int n) {
    __shared__ int deg[256], offs[256], curs[256], s[256];
    int b = blockIdx.x, tid = threadIdx.x;
    int e0 = bucketOff[b], e1 = bucketOff[b + 1];
    deg[tid] = 0;
    curs[tid] = 0;
    __syncthreads();
    for (int t = e0 + tid; t < e1; t += 256)
        atomicAdd(&deg[epart[t].y & 255], 1);
    __syncthreads();
    int v = deg[tid];
    s[tid] = v;
    __syncthreads();
    int acc = v;
    for (int off = 1; off < 256; off <<= 1) {
        int t = (tid >= off) ? s[tid - off] : 0;
        __syncthreads();
        acc += t;
        s[tid] = acc;
        __syncthreads();
    }
    int excl = acc - v;
    offs[tid] = excl;
    int node = (b << 8) + tid;
    if (node < n) rowptr[node] = e0 + excl;
    __syncthreads();
    for (int t = e0 + tid; t < e1; t += 256) {
        int2 e = epart[t];
        int l = e.y & 255;
        int pos = e0 + offs[l] + atomicAdd(&curs[l], 1);
        colidx[pos] = e.x;
    }
}

// ======================= bf16 weight packing ==========
// P[(t*4+kc)*64+lane][j] = bf16(W[kc*32+quad*8+j][16t+(lane&15)])
__global__ void k_pack(const float* __restrict__ W, u16* __restrict__ P) {
    int i = blockIdx.x * 256 + threadIdx.x;   // 0..2047
    if (i >= 2048) return;
    int lane = i & 63, kc = (i >> 6) & 3, t = i >> 8;
    int quad = lane >> 4, col = 16 * t + (lane & 15);
    #pragma unroll
    for (int j = 0; j < 8; ++j) {
        int k = kc * 32 + quad * 8 + j;
        P[(size_t)i * 8 + j] = f2b(W[k * HF + col]);
    }
}

// ======================= MFMA GEMM (+bias, + optional fused alpha dots) ==========
// block = 256 (4 waves); wave w owns rows m0+16w..+15, all 128 cols (8 n-tiles).
// C/D layout: col = lane&15 (in tile), row = quad*4 + reg
template<bool A32>
__global__ __launch_bounds__(256) void k_gemm_mfma(const u16* __restrict__ Ab,
                                                   const float* __restrict__ Af,
                                                   const u16* __restrict__ Bp,
                                                   const float* __restrict__ bias,
                                                   const float* __restrict__ a_s,
                                                   const float* __restrict__ a_d,
                                                   float* __restrict__ as_,
                                                   float* __restrict__ ad_,
                                                   u16* __restrict__ C, int M) {
    int lane = threadIdx.x & 63;
    int wave = threadIdx.x >> 6;
    int quad = lane >> 4, l16 = lane & 15;
    int m0 = blockIdx.x * 64 + wave * 16;
    int arow = m0 + l16;
    bool aval = arow < M;
    const bf16x8* Av = A32 ? nullptr : (const bf16x8*)(Ab + (size_t)arow * HF);
    const bf16x8* Bv = (const bf16x8*)Bp;
    f32x4 acc[8] = {};

    #pragma unroll
    for (int kc = 0; kc < 4; ++kc) {
        bf16x8 a = {};
        if (aval) {
            if constexpr (A32) {
                const float* ap = Af + (size_t)arow * HF + kc * 32 + quad * 8;
                float4 f0 = *(const float4*)ap;
                float4 f1 = *(const float4*)(ap + 4);
                a[0] = (short)f2b(f0.x); a[1] = (short)f2b(f0.y);
                a[2] = (short)f2b(f0.z); a[3] = (short)f2b(f0.w);
                a[4] = (short)f2b(f1.x); a[5] = (short)f2b(f1.y);
                a[6] = (short)f2b(f1.z); a[7] = (short)f2b(f1.w);
            } else {
                a = Av[kc * 4 + quad];
            }
        }
        #pragma unroll
        for (int t = 0; t < 8; ++t)
            acc[t] = __builtin_amdgcn_mfma_f32_16x16x32_bf16(a, Bv[t * 256 + kc * 64 + lane],
                                                             acc[t], 0, 0, 0);
    }

    int orow0 = m0 + quad * 4;
    #pragma unroll
    for (int t = 0; t < 8; ++t) {
        float b4 = bias ? bias[t * 16 + l16] : 0.f;
        #pragma unroll
        for (int r = 0; r < 4; ++r) {
            int orow = orow0 + r;
            if (orow < M) C[(size_t)orow * HF + t * 16 + l16] = f2b(acc[t][r] + b4);
        }
    }

    // fused attention dots: as_[row] = hp[row].a_s, ad_[row] = hp[row].a_d
    if (as_) {
        float avs[8], avd[8];
        #pragma unroll
        for (int t = 0; t < 8; ++t) {
            avs[t] = a_s[t * 16 + l16];
            avd[t] = a_d[t * 16 + l16];
        }
        #pragma unroll
        for (int r = 0; r < 4; ++r) {
            float ps = 0.f, pd = 0.f;
            #pragma unroll
            for (int t = 0; t < 8; ++t) {
                ps = fmaf(acc[t][r], avs[t], ps);
                pd = fmaf(acc[t][r], avd[t], pd);
            }
            #pragma unroll
            for (int o = 1; o < 16; o <<= 1) {
                ps += __shfl_xor(ps, o);
                pd += __shfl_xor(pd, o);
            }
            int row = orow0 + r;
            if (l16 == 0 && row < M) { as_[row] = ps; ad_[row] = pd; }
        }
    }
}

// ======================= per-dst softmax aggregation (bf16 gather) ==========
__global__ __launch_bounds__(256) void k_agg(const int* __restrict__ rowptr,
                                             const int* __restrict__ colidx,
                                             const u16* __restrict__ hpb,
                                             const float* __restrict__ as_,
                                             const float* __restrict__ ad_,
                                             const float* __restrict__ bl,
                                             u16* __restrict__ hout,
                                             int n, int relu) {
    int wave = (blockIdx.x * 256 + threadIdx.x) >> 6;
    int lane = threadIdx.x & 63;
    if (wave >= n) return;
    int beg = rowptr[wave], end = rowptr[wave + 1];
    int deg = end - beg;
    float adi = ad_[wave];

    int  srcl = (lane < deg) ? colidx[beg + lane] : 0;
    float el = -1e30f;
    if (lane < deg) {
        float e = as_[srcl] + adi;
        el = e > 0.f ? e : NEG * e;
    }

    float m = el;
    for (int jj = beg + 64 + lane; jj < end; jj += 64) {
        float e = as_[colidx[jj]] + adi;
        e = e > 0.f ? e : NEG * e;
        m = fmaxf(m, e);
    }
    #pragma unroll
    for (int off = 32; off; off >>= 1) m = fmaxf(m, __shfl_xor(m, off));

    float ex = (lane < deg) ? __expf(el - m) : 0.f;
    float ssum = ex;
    for (int jj = beg + 64 + lane; jj < end; jj += 64) {
        float e = as_[colidx[jj]] + adi;
        e = e > 0.f ? e : NEG * e;
        ssum += __expf(e - m);
    }
    #pragma unroll
    for (int off = 32; off; off >>= 1) ssum += __shfl_xor(ssum, off);
    float inv = 1.f / ssum;
    float wl = ex * inv;

    float acc0 = 0.f, acc1 = 0.f;
    int cnt = deg < 64 ? deg : 64;
    int t = 0;
    for (; t + 4 <= cnt; t += 4) {
        int   s0 = __shfl(srcl, t    ), s1 = __shfl(srcl, t + 1);
        int   s2 = __shfl(srcl, t + 2), s3 = __shfl(srcl, t + 3);
        float w0 = __shfl(wl,   t    ), w1 = __shfl(wl,   t + 1);
        float w2 = __shfl(wl,   t + 2), w3 = __shfl(wl,   t + 3);
        u32 v0 = ((const u32*)(hpb + (size_t)s0 * HF))[lane];
        u32 v1 = ((const u32*)(hpb + (size_t)s1 * HF))[lane];
        u32 v2 = ((const u32*)(hpb + (size_t)s2 * HF))[lane];
        u32 v3 = ((const u32*)(hpb + (size_t)s3 * HF))[lane];
        acc0 = fmaf(w0, blo(v0), acc0); acc1 = fmaf(w0, bhi(v0), acc1);
        acc0 = fmaf(w1, blo(v1), acc0); acc1 = fmaf(w1, bhi(v1), acc1);
        acc0 = fmaf(w2, blo(v2), acc0); acc1 = fmaf(w2, bhi(v2), acc1);
        acc0 = fmaf(w3, blo(v3), acc0); acc1 = fmaf(w3, bhi(v3), acc1);
    }
    for (; t < cnt; ++t) {
        int   s0 = __shfl(srcl, t);
        float w0 = __shfl(wl,   t);
        u32 v0 = ((const u32*)(hpb + (size_t)s0 * HF))[lane];
        acc0 = fmaf(w0, blo(v0), acc0); acc1 = fmaf(w0, bhi(v0), acc1);
    }
    for (int jj = beg + 64; jj < end; ++jj) {   // rare deg>64 tail
        int srcn = colidx[jj];
        float e = as_[srcn] + adi;
        e = e > 0.f ? e : NEG * e;
        float w = __expf(e - m) * inv;
        u32 v = ((const u32*)(hpb + (size_t)srcn * HF))[lane];
        acc0 = fmaf(w, blo(v), acc0); acc1 = fmaf(w, bhi(v), acc1);
    }

    float2 bb = ((const float2*)bl)[lane];
    acc0 += bb.x; acc1 += bb.y;
    if (relu) { acc0 = fmaxf(acc0, 0.f); acc1 = fmaxf(acc1, 0.f); }
    u32 o = ((u32)f2b(acc1) << 16) | (u32)f2b(acc0);
    ((u32*)(hout + (size_t)wave * HF))[lane] = o;
}

// ======================= pooling over sorted batch (bf16 h, fp32 accum) ==========
__global__ void k_pool_zero(float* pooled) {
    pooled[blockIdx.x * HF + threadIdx.x] = 0.f;
}

#define PROWS 128
__global__ __launch_bounds__(128) void k_pool(const u16* __restrict__ hb,
                                              const int* __restrict__ batch,
                                              float* __restrict__ pooled, int n) {
    int r0 = blockIdx.x * PROWS;
    int r1 = min(r0 + PROWS, n);
    if (r0 >= r1) return;
    int t = threadIdx.x;
    int cur = batch[r0];
    float acc = 0.f;
    for (int i = r0; i < r1; ++i) {
        int b = batch[i];
        if (b != cur) {
            atomicAdd(&pooled[cur * HF + t], acc);
            acc = 0.f;
            cur = b;
        }
        acc += __builtin_bit_cast(float, (u32)hb[(size_t)i * HF + t] << 16);
    }
    atomicAdd(&pooled[cur * HF + t], acc);
}

__global__ void k_final(const float* __restrict__ pooled, const float* __restrict__ Wf,
                        const float* __restrict__ bf, float* __restrict__ out) {
    int g = blockIdx.x, o = threadIdx.x;   // 64 threads
    float acc = bf[o];
    #pragma unroll 8
    for (int k = 0; k < HF; ++k) acc = fmaf(pooled[g * HF + k], Wf[k * OUTF + o], acc);
    out[g * OUTF + o] = acc;
}

// ======================= launch =======================
extern "C" void kernel_launch(void* const* d_in, const int* in_sizes, int n_in,
                              void* d_out, int out_size, void* d_ws, size_t ws_size,
                              hipStream_t stream) {
    const float* x      = (const float*)d_in[0];
    const int*   edge   = (const int*)d_in[1];
    const int*   batch  = (const int*)d_in[2];
    const float* W0     = (const float*)d_in[3];
    const float* b0     = (const float*)d_in[4];
    const float* Wl     = (const float*)d_in[5];
    const float* a_src  = (const float*)d_in[6];
    const float* a_dst  = (const float*)d_in[7];
    const float* bl     = (const float*)d_in[8];
    const float* Wf     = (const float*)d_in[9];
    const float* bf     = (const float*)d_in[10];
    float* out = (float*)d_out;

    const int N  = in_sizes[2];
    const int E  = in_sizes[1] / 2;
    const int Et = E + N;
    const int L  = 3;
    const int NB = (N + 255) >> 8;               // buckets (<= 256)

    char* ws = (char*)d_ws;
    size_t off = 0;
    auto alloc = [&](size_t bytes) { char* p = ws + off; off += (bytes + 255) & ~(size_t)255; return p; };
    u16*   hb      = (u16*)alloc((size_t)N * HF * 2);
    u16*   hpb     = (u16*)alloc((size_t)N * HF * 2);
    u16*   Wp      = (u16*)alloc((size_t)4 * HF * HF * 2);
    float* as_     = (float*)alloc((size_t)N * 4);
    float* ad_     = (float*)alloc((size_t)N * 4);
    int*   rowptr  = (int*)alloc((size_t)(N + 1) * 4);
    int*   colidx  = (int*)alloc((size_t)Et * 4);
    int2*  epart   = (int2*)alloc((size_t)Et * 8);
    int*   bucketCnt = (int*)alloc(256 * 4);
    int*   bucketOff = (int*)alloc(257 * 4);
    int*   bucketCur = (int*)alloc(256 * 4);
    float* pooled  = (float*)alloc((size_t)GCOUNT * HF * 4);
    (void)ws_size; (void)n_in; (void)out_size;

    const int wb4   = (N + 3) / 4;               // wave-per-node kernels
    const int gemmb = (N + 63) / 64;
    const int partb = (Et + CH - 1) / CH;

    const int* esrc = edge;
    const int* edst = edge + E;

    // --- pack weights ---
    k_pack<<<8, 256, 0, stream>>>(W0, Wp);
    for (int l = 0; l < L; ++l)
        k_pack<<<8, 256, 0, stream>>>(Wl + (size_t)l * HF * HF, Wp + (size_t)(l + 1) * HF * HF);

    // --- bucketed dst-CSR build (reused across all 3 layers) ---
    k_zero256<<<1, 256, 0, stream>>>(bucketCnt);
    k_bhist<<<partb, 256, 0, stream>>>(edst, bucketCnt, E, Et);
    k_bscan<<<1, 256, 0, stream>>>(bucketCnt, bucketOff, bucketCur, rowptr, NB, Et, N);
    k_bpart<<<partb, 256, 0, stream>>>(esrc, edst, bucketCur, epart, E, Et);
    k_bcsr<<<NB, 256, 0, stream>>>(epart, bucketOff, rowptr, colidx, N);

    // --- h = x @ W0 + b0 (fp32 A, fused cvt) ---
    k_gemm_mfma<true><<<gemmb, 256, 0, stream>>>(nullptr, x, Wp, b0,
                                                 nullptr, nullptr, nullptr, nullptr, hb, N);

    // --- GAT layers (alpha dots fused into GEMM epilogue) ---
    for (int l = 0; l < L; ++l) {
        k_gemm_mfma<false><<<gemmb, 256, 0, stream>>>(hb, nullptr,
                                                      Wp + (size_t)(l + 1) * HF * HF, nullptr,
                                                      a_src + l * HF, a_dst + l * HF,
                                                      as_, ad_, hpb, N);
        k_agg<<<wb4, 256, 0, stream>>>(rowptr, colidx, hpb, as_, ad_, bl + l * HF, hb, N,
                                       (l < L - 1) ? 1 : 0);
    }

    // --- pooling + final linear ---
    k_pool_zero<<<GCOUNT, HF, 0, stream>>>(pooled);
    k_pool<<<(N + PROWS - 1) / PROWS, 128, 0, stream>>>(hb, batch, pooled, N);
    k_final<<<GCOUNT, OUTF, 0, stream>>>(pooled, Wf, bf, out);
}

// Round 7
// 345.020 us; speedup vs baseline: 3.1897x; 1.0394x over previous
//
#include <hip/hip_runtime.h>
#include <hip/hip_bf16.h>
#include <math.h>

#define HF 128          // hidden / input feature dim
#define GCOUNT 64       // graphs in batch
#define OUTF 64         // final output features
#define NEG 0.2f        // leaky relu slope
#define CH 2048         // edges per partition block
#define BCAP 8192       // per-bucket edge capacity (expected ~4340, +50 sigma)

typedef unsigned short u16;
typedef unsigned int   u32;
typedef short bf16x8 __attribute__((ext_vector_type(8)));
typedef float f32x4  __attribute__((ext_vector_type(4)));

// fp32 -> bf16 (RNE) bit trick
__device__ __forceinline__ u16 f2b(float f) {
    u32 u = __builtin_bit_cast(u32, f);
    u32 r = (u + 0x7FFFu + ((u >> 16) & 1u)) >> 16;
    return (u16)r;
}
__device__ __forceinline__ float blo(u32 u) { return __builtin_bit_cast(float, u << 16); }
__device__ __forceinline__ float bhi(u32 u) { return __builtin_bit_cast(float, u & 0xFFFF0000u); }

// ======================= bucketed CSR build (fixed-capacity buckets) =======================
// bucket b = dst >> 8; bucket region = [b*BCAP, b*BCAP + cnt_b). No global scan needed.

__global__ void k_binit(int* bucketCur) {
    bucketCur[threadIdx.x] = threadIdx.x * BCAP;    // 256 threads
}

// single pass: LDS hist -> chunk reservation -> packed scatter (src<<8 | dst&255)
__global__ __launch_bounds__(256) void k_bpart(const int* __restrict__ esrc,
                                               const int* __restrict__ edst,
                                               int* __restrict__ bucketCur,
                                               u32* __restrict__ epart, int ne, int ntot) {
    __shared__ int cnt[256];
    __shared__ int base[256];
    int t0 = blockIdx.x * CH, t1 = min(t0 + CH, ntot);
    cnt[threadIdx.x] = 0;
    __syncthreads();
    for (int t = t0 + threadIdx.x; t < t1; t += 256) {
        int d = (t < ne) ? edst[t] : t - ne;       // tail = self loops
        atomicAdd(&cnt[d >> 8], 1);
    }
    __syncthreads();
    int c = cnt[threadIdx.x];
    base[threadIdx.x] = c ? atomicAdd(&bucketCur[threadIdx.x], c) : 0;
    cnt[threadIdx.x] = 0;
    __syncthreads();
    for (int t = t0 + threadIdx.x; t < t1; t += 256) {
        int s, d;
        if (t < ne) { s = esrc[t]; d = edst[t]; }
        else        { s = t - ne; d = s; }
        int b = d >> 8;
        int pos = base[b] + atomicAdd(&cnt[b], 1);
        epart[pos] = ((u32)s << 8) | (u32)(d & 255);
    }
}

// one block per bucket: local degree hist + scan -> rowbeg/rowend + colidx scatter
__global__ __launch_bounds__(256) void k_bcsr(const u32* __restrict__ epart,
                                              const int* __restrict__ bucketCur,
                                              int* __restrict__ rowbeg,
                                              int* __restrict__ rowend,
                                              int* __restrict__ colidx, int n) {
    __shared__ int deg[256], offs[256], curs[256], s[256];
    int b = blockIdx.x, tid = threadIdx.x;
    int e0 = b * BCAP, e1 = bucketCur[b];
    deg[tid] = 0;
    curs[tid] = 0;
    __syncthreads();
    for (int t = e0 + tid; t < e1; t += 256)
        atomicAdd(&deg[epart[t] & 255u], 1);
    __syncthreads();
    int v = deg[tid];
    s[tid] = v;
    __syncthreads();
    int acc = v;
    for (int off = 1; off < 256; off <<= 1) {
        int t = (tid >= off) ? s[tid - off] : 0;
        __syncthreads();
        acc += t;
        s[tid] = acc;
        __syncthreads();
    }
    int excl = acc - v;
    offs[tid] = excl;
    int node = (b << 8) + tid;
    if (node < n) {
        rowbeg[node] = e0 + excl;
        rowend[node] = e0 + excl + v;
    }
    __syncthreads();
    for (int t = e0 + tid; t < e1; t += 256) {
        u32 e = epart[t];
        int l = e & 255u;
        int pos = e0 + offs[l] + atomicAdd(&curs[l], 1);
        colidx[pos] = (int)(e >> 8);
    }
}

// ======================= bf16 weight packing (all 4 matrices, one launch) ==========
// P[m][(t*4+kc)*64+lane][j] = bf16(W_m[kc*32+quad*8+j][16t+(lane&15)])
__global__ void k_pack(const float* __restrict__ W0, const float* __restrict__ Wl,
                       u16* __restrict__ P) {
    int m = blockIdx.x >> 3;                       // 0..3: W0, Wl[0..2]
    int i = (blockIdx.x & 7) * 256 + threadIdx.x;  // 0..2047
    const float* W = (m == 0) ? W0 : Wl + (size_t)(m - 1) * HF * HF;
    u16* Pm = P + (size_t)m * HF * HF;
    int lane = i & 63, kc = (i >> 6) & 3, t = i >> 8;
    int quad = lane >> 4, col = 16 * t + (lane & 15);
    #pragma unroll
    for (int j = 0; j < 8; ++j) {
        int k = kc * 32 + quad * 8 + j;
        Pm[(size_t)i * 8 + j] = f2b(W[k * HF + col]);
    }
}

// ======================= MFMA GEMM (+bias, + optional fused alpha dots) ==========
// block = 256 (4 waves); wave w owns rows m0+16w..+15, all 128 cols (8 n-tiles).
// C/D layout: col = lane&15 (in tile), row = quad*4 + reg
template<bool A32>
__global__ __launch_bounds__(256) void k_gemm_mfma(const u16* __restrict__ Ab,
                                                   const float* __restrict__ Af,
                                                   const u16* __restrict__ Bp,
                                                   const float* __restrict__ bias,
                                                   const float* __restrict__ a_s,
                                                   const float* __restrict__ a_d,
                                                   float* __restrict__ as_,
                                                   float* __restrict__ ad_,
                                                   u16* __restrict__ C, int M) {
    int lane = threadIdx.x & 63;
    int wave = threadIdx.x >> 6;
    int quad = lane >> 4, l16 = lane & 15;
    int m0 = blockIdx.x * 64 + wave * 16;
    int arow = m0 + l16;
    bool aval = arow < M;
    const bf16x8* Av = A32 ? nullptr : (const bf16x8*)(Ab + (size_t)arow * HF);
    const bf16x8* Bv = (const bf16x8*)Bp;
    f32x4 acc[8] = {};

    #pragma unroll
    for (int kc = 0; kc < 4; ++kc) {
        bf16x8 a = {};
        if (aval) {
            if constexpr (A32) {
                const float* ap = Af + (size_t)arow * HF + kc * 32 + quad * 8;
                float4 f0 = *(const float4*)ap;
                float4 f1 = *(const float4*)(ap + 4);
                a[0] = (short)f2b(f0.x); a[1] = (short)f2b(f0.y);
                a[2] = (short)f2b(f0.z); a[3] = (short)f2b(f0.w);
                a[4] = (short)f2b(f1.x); a[5] = (short)f2b(f1.y);
                a[6] = (short)f2b(f1.z); a[7] = (short)f2b(f1.w);
            } else {
                a = Av[kc * 4 + quad];
            }
        }
        #pragma unroll
        for (int t = 0; t < 8; ++t)
            acc[t] = __builtin_amdgcn_mfma_f32_16x16x32_bf16(a, Bv[t * 256 + kc * 64 + lane],
                                                             acc[t], 0, 0, 0);
    }

    int orow0 = m0 + quad * 4;
    #pragma unroll
    for (int t = 0; t < 8; ++t) {
        float b4 = bias ? bias[t * 16 + l16] : 0.f;
        #pragma unroll
        for (int r = 0; r < 4; ++r) {
            int orow = orow0 + r;
            if (orow < M) C[(size_t)orow * HF + t * 16 + l16] = f2b(acc[t][r] + b4);
        }
    }

    // fused attention dots: as_[row] = hp[row].a_s, ad_[row] = hp[row].a_d
    if (as_) {
        float avs[8], avd[8];
        #pragma unroll
        for (int t = 0; t < 8; ++t) {
            avs[t] = a_s[t * 16 + l16];
            avd[t] = a_d[t * 16 + l16];
        }
        #pragma unroll
        for (int r = 0; r < 4; ++r) {
            float ps = 0.f, pd = 0.f;
            #pragma unroll
            for (int t = 0; t < 8; ++t) {
                ps = fmaf(acc[t][r], avs[t], ps);
                pd = fmaf(acc[t][r], avd[t], pd);
            }
            #pragma unroll
            for (int o = 1; o < 16; o <<= 1) {
                ps += __shfl_xor(ps, o);
                pd += __shfl_xor(pd, o);
            }
            int row = orow0 + r;
            if (l16 == 0 && row < M) { as_[row] = ps; ad_[row] = pd; }
        }
    }
}

// ======================= per-dst softmax aggregation (bf16 gather) ==========
__global__ __launch_bounds__(256) void k_agg(const int* __restrict__ rowbeg,
                                             const int* __restrict__ rowend,
                                             const int* __restrict__ colidx,
                                             const u16* __restrict__ hpb,
                                             const float* __restrict__ as_,
                                             const float* __restrict__ ad_,
                                             const float* __restrict__ bl,
                                             u16* __restrict__ hout,
                                             int n, int relu) {
    int wave = (blockIdx.x * 256 + threadIdx.x) >> 6;
    int lane = threadIdx.x & 63;
    if (wave >= n) return;
    int beg = rowbeg[wave], end = rowend[wave];
    int deg = end - beg;
    float adi = ad_[wave];

    int  srcl = (lane < deg) ? colidx[beg + lane] : 0;
    float el = -1e30f;
    if (lane < deg) {
        float e = as_[srcl] + adi;
        el = e > 0.f ? e : NEG * e;
    }

    float m = el;
    for (int jj = beg + 64 + lane; jj < end; jj += 64) {
        float e = as_[colidx[jj]] + adi;
        e = e > 0.f ? e : NEG * e;
        m = fmaxf(m, e);
    }
    #pragma unroll
    for (int off = 32; off; off >>= 1) m = fmaxf(m, __shfl_xor(m, off));

    float ex = (lane < deg) ? __expf(el - m) : 0.f;
    float ssum = ex;
    for (int jj = beg + 64 + lane; jj < end; jj += 64) {
        float e = as_[colidx[jj]] + adi;
        e = e > 0.f ? e : NEG * e;
        ssum += __expf(e - m);
    }
    #pragma unroll
    for (int off = 32; off; off >>= 1) ssum += __shfl_xor(ssum, off);
    float inv = 1.f / ssum;
    float wl = ex * inv;

    float acc0 = 0.f, acc1 = 0.f;
    int cnt = deg < 64 ? deg : 64;
    int t = 0;
    for (; t + 4 <= cnt; t += 4) {
        int   s0 = __shfl(srcl, t    ), s1 = __shfl(srcl, t + 1);
        int   s2 = __shfl(srcl, t + 2), s3 = __shfl(srcl, t + 3);
        float w0 = __shfl(wl,   t    ), w1 = __shfl(wl,   t + 1);
        float w2 = __shfl(wl,   t + 2), w3 = __shfl(wl,   t + 3);
        u32 v0 = ((const u32*)(hpb + (size_t)s0 * HF))[lane];
        u32 v1 = ((const u32*)(hpb + (size_t)s1 * HF))[lane];
        u32 v2 = ((const u32*)(hpb + (size_t)s2 * HF))[lane];
        u32 v3 = ((const u32*)(hpb + (size_t)s3 * HF))[lane];
        acc0 = fmaf(w0, blo(v0), acc0); acc1 = fmaf(w0, bhi(v0), acc1);
        acc0 = fmaf(w1, blo(v1), acc0); acc1 = fmaf(w1, bhi(v1), acc1);
        acc0 = fmaf(w2, blo(v2), acc0); acc1 = fmaf(w2, bhi(v2), acc1);
        acc0 = fmaf(w3, blo(v3), acc0); acc1 = fmaf(w3, bhi(v3), acc1);
    }
    for (; t < cnt; ++t) {
        int   s0 = __shfl(srcl, t);
        float w0 = __shfl(wl,   t);
        u32 v0 = ((const u32*)(hpb + (size_t)s0 * HF))[lane];
        acc0 = fmaf(w0, blo(v0), acc0); acc1 = fmaf(w0, bhi(v0), acc1);
    }
    for (int jj = beg + 64; jj < end; ++jj) {   // rare deg>64 tail
        int srcn = colidx[jj];
        float e = as_[srcn] + adi;
        e = e > 0.f ? e : NEG * e;
        float w = __expf(e - m) * inv;
        u32 v = ((const u32*)(hpb + (size_t)srcn * HF))[lane];
        acc0 = fmaf(w, blo(v), acc0); acc1 = fmaf(w, bhi(v), acc1);
    }

    float2 bb = ((const float2*)bl)[lane];
    acc0 += bb.x; acc1 += bb.y;
    if (relu) { acc0 = fmaxf(acc0, 0.f); acc1 = fmaxf(acc1, 0.f); }
    u32 o = ((u32)f2b(acc1) << 16) | (u32)f2b(acc0);
    ((u32*)(hout + (size_t)wave * HF))[lane] = o;
}

// ======================= pooling over sorted batch (bf16 h, fp32 accum) ==========
__global__ void k_pool_zero(float* pooled) {
    pooled[blockIdx.x * HF + threadIdx.x] = 0.f;
}

#define PROWS 128
__global__ __launch_bounds__(128) void k_pool(const u16* __restrict__ hb,
                                              const int* __restrict__ batch,
                                              float* __restrict__ pooled, int n) {
    int r0 = blockIdx.x * PROWS;
    int r1 = min(r0 + PROWS, n);
    if (r0 >= r1) return;
    int t = threadIdx.x;
    int cur = batch[r0];
    float acc = 0.f;
    for (int i = r0; i < r1; ++i) {
        int b = batch[i];
        if (b != cur) {
            atomicAdd(&pooled[cur * HF + t], acc);
            acc = 0.f;
            cur = b;
        }
        acc += __builtin_bit_cast(float, (u32)hb[(size_t)i * HF + t] << 16);
    }
    atomicAdd(&pooled[cur * HF + t], acc);
}

__global__ void k_final(const float* __restrict__ pooled, const float* __restrict__ Wf,
                        const float* __restrict__ bf, float* __restrict__ out) {
    int g = blockIdx.x, o = threadIdx.x;   // 64 threads
    float acc = bf[o];
    #pragma unroll 8
    for (int k = 0; k < HF; ++k) acc = fmaf(pooled[g * HF + k], Wf[k * OUTF + o], acc);
    out[g * OUTF + o] = acc;
}

// ======================= launch =======================
extern "C" void kernel_launch(void* const* d_in, const int* in_sizes, int n_in,
                              void* d_out, int out_size, void* d_ws, size_t ws_size,
                              hipStream_t stream) {
    const float* x      = (const float*)d_in[0];
    const int*   edge   = (const int*)d_in[1];
    const int*   batch  = (const int*)d_in[2];
    const float* W0     = (const float*)d_in[3];
    const float* b0     = (const float*)d_in[4];
    const float* Wl     = (const float*)d_in[5];
    const float* a_src  = (const float*)d_in[6];
    const float* a_dst  = (const float*)d_in[7];
    const float* bl     = (const float*)d_in[8];
    const float* Wf     = (const float*)d_in[9];
    const float* bf     = (const float*)d_in[10];
    float* out = (float*)d_out;

    const int N  = in_sizes[2];
    const int E  = in_sizes[1] / 2;
    const int Et = E + N;
    const int L  = 3;
    const int NB = (N + 255) >> 8;               // buckets (<= 256)

    char* ws = (char*)d_ws;
    size_t off = 0;
    auto alloc = [&](size_t bytes) { char* p = ws + off; off += (bytes + 255) & ~(size_t)255; return p; };
    u16*   hb      = (u16*)alloc((size_t)N * HF * 2);
    u16*   hpb     = (u16*)alloc((size_t)N * HF * 2);
    u16*   Wp      = (u16*)alloc((size_t)4 * HF * HF * 2);
    float* as_     = (float*)alloc((size_t)N * 4);
    float* ad_     = (float*)alloc((size_t)N * 4);
    int*   rowbeg  = (int*)alloc((size_t)N * 4);
    int*   rowend  = (int*)alloc((size_t)N * 4);
    int*   colidx  = (int*)alloc((size_t)NB * BCAP * 4);
    u32*   epart   = (u32*)alloc((size_t)NB * BCAP * 4);
    int*   bucketCur = (int*)alloc(256 * 4);
    float* pooled  = (float*)alloc((size_t)GCOUNT * HF * 4);
    (void)ws_size; (void)n_in; (void)out_size;

    const int wb4   = (N + 3) / 4;               // wave-per-node kernels
    const int gemmb = (N + 63) / 64;
    const int partb = (Et + CH - 1) / CH;

    const int* esrc = edge;
    const int* edst = edge + E;

    // --- pack weights (one launch, all 4 matrices) ---
    k_pack<<<32, 256, 0, stream>>>(W0, Wl, Wp);

    // --- bucketed dst-CSR build (reused across all 3 layers) ---
    k_binit<<<1, 256, 0, stream>>>(bucketCur);
    k_bpart<<<partb, 256, 0, stream>>>(esrc, edst, bucketCur, epart, E, Et);
    k_bcsr<<<NB, 256, 0, stream>>>(epart, bucketCur, rowbeg, rowend, colidx, N);

    // --- h = x @ W0 + b0 (fp32 A, fused cvt) ---
    k_gemm_mfma<true><<<gemmb, 256, 0, stream>>>(nullptr, x, Wp, b0,
                                                 nullptr, nullptr, nullptr, nullptr, hb, N);

    // --- GAT layers (alpha dots fused into GEMM epilogue) ---
    for (int l = 0; l < L; ++l) {
        k_gemm_mfma<false><<<gemmb, 256, 0, stream>>>(hb, nullptr,
                                                      Wp + (size_t)(l + 1) * HF * HF, nullptr,
                                                      a_src + l * HF, a_dst + l * HF,
                                                      as_, ad_, hpb, N);
        k_agg<<<wb4, 256, 0, stream>>>(rowbeg, rowend, colidx, hpb, as_, ad_, bl + l * HF, hb, N,
                                       (l < L - 1) ? 1 : 0);
    }

    // --- pooling + final linear ---
    k_pool_zero<<<GCOUNT, HF, 0, stream>>>(pooled);
    k_pool<<<(N + PROWS - 1) / PROWS, 128, 0, stream>>>(hb, batch, pooled, N);
    k_final<<<GCOUNT, OUTF, 0, stream>>>(pooled, Wf, bf, out);
}

// Round 8
// 338.232 us; speedup vs baseline: 3.2537x; 1.0201x over previous
//
#include <hip/hip_runtime.h>
#include <hip/hip_bf16.h>
#include <math.h>

#define HF 128          // hidden / input feature dim
#define GCOUNT 64       // graphs in batch
#define OUTF 64         // final output features
#define NEG 0.2f        // leaky relu slope
#define CH 2048         // edges per partition block
#define BCAP 8192       // per-bucket edge capacity (expected ~4340, +50 sigma)

typedef unsigned short u16;
typedef unsigned int   u32;
typedef short bf16x8 __attribute__((ext_vector_type(8)));
typedef float f32x4  __attribute__((ext_vector_type(4)));

// fp32 -> bf16 (RNE) bit trick
__device__ __forceinline__ u16 f2b(float f) {
    u32 u = __builtin_bit_cast(u32, f);
    u32 r = (u + 0x7FFFu + ((u >> 16) & 1u)) >> 16;
    return (u16)r;
}
__device__ __forceinline__ float blo(u32 u) { return __builtin_bit_cast(float, u << 16); }
__device__ __forceinline__ float bhi(u32 u) { return __builtin_bit_cast(float, u & 0xFFFF0000u); }

// ======================= bucketed CSR build (fixed-capacity buckets) =======================
// bucket b = dst >> 8; bucket region = [b*BCAP, b*BCAP + cnt_b). No global scan needed.

// block 0: init bucketCur; blocks 1..32: zero pooled (folds k_pool_zero in)
__global__ void k_binit(int* bucketCur, float* pooled) {
    if (blockIdx.x == 0) bucketCur[threadIdx.x] = threadIdx.x * BCAP;
    else pooled[(blockIdx.x - 1) * 256 + threadIdx.x] = 0.f;
}

// single pass: LDS hist -> chunk reservation -> packed scatter (src<<8 | dst&255)
__global__ __launch_bounds__(256) void k_bpart(const int* __restrict__ esrc,
                                               const int* __restrict__ edst,
                                               int* __restrict__ bucketCur,
                                               u32* __restrict__ epart, int ne, int ntot) {
    __shared__ int cnt[256];
    __shared__ int base[256];
    int t0 = blockIdx.x * CH, t1 = min(t0 + CH, ntot);
    cnt[threadIdx.x] = 0;
    __syncthreads();
    for (int t = t0 + threadIdx.x; t < t1; t += 256) {
        int d = (t < ne) ? edst[t] : t - ne;       // tail = self loops
        atomicAdd(&cnt[d >> 8], 1);
    }
    __syncthreads();
    int c = cnt[threadIdx.x];
    base[threadIdx.x] = c ? atomicAdd(&bucketCur[threadIdx.x], c) : 0;
    cnt[threadIdx.x] = 0;
    __syncthreads();
    for (int t = t0 + threadIdx.x; t < t1; t += 256) {
        int s, d;
        if (t < ne) { s = esrc[t]; d = edst[t]; }
        else        { s = t - ne; d = s; }
        int b = d >> 8;
        int pos = base[b] + atomicAdd(&cnt[b], 1);
        epart[pos] = ((u32)s << 8) | (u32)(d & 255);
    }
}

// one block per bucket: local degree hist + scan -> rowbeg/rowend + colidx scatter
__global__ __launch_bounds__(256) void k_bcsr(const u32* __restrict__ epart,
                                              const int* __restrict__ bucketCur,
                                              int* __restrict__ rowbeg,
                                              int* __restrict__ rowend,
                                              int* __restrict__ colidx, int n) {
    __shared__ int deg[256], offs[256], curs[256], s[256];
    int b = blockIdx.x, tid = threadIdx.x;
    int e0 = b * BCAP, e1 = bucketCur[b];
    deg[tid] = 0;
    curs[tid] = 0;
    __syncthreads();
    for (int t = e0 + tid; t < e1; t += 256)
        atomicAdd(&deg[epart[t] & 255u], 1);
    __syncthreads();
    int v = deg[tid];
    s[tid] = v;
    __syncthreads();
    int acc = v;
    for (int off = 1; off < 256; off <<= 1) {
        int t = (tid >= off) ? s[tid - off] : 0;
        __syncthreads();
        acc += t;
        s[tid] = acc;
        __syncthreads();
    }
    int excl = acc - v;
    offs[tid] = excl;
    int node = (b << 8) + tid;
    if (node < n) {
        rowbeg[node] = e0 + excl;
        rowend[node] = e0 + excl + v;
    }
    __syncthreads();
    for (int t = e0 + tid; t < e1; t += 256) {
        u32 e = epart[t];
        int l = e & 255u;
        int pos = e0 + offs[l] + atomicAdd(&curs[l], 1);
        colidx[pos] = (int)(e >> 8);
    }
}

// ======================= bf16 weight packing (all 4 matrices, one launch) ==========
// P[m][(t*4+kc)*64+lane][j] = bf16(W_m[kc*32+quad*8+j][16t+(lane&15)])
__global__ void k_pack(const float* __restrict__ W0, const float* __restrict__ Wl,
                       u16* __restrict__ P) {
    int m = blockIdx.x >> 3;                       // 0..3: W0, Wl[0..2]
    int i = (blockIdx.x & 7) * 256 + threadIdx.x;  // 0..2047
    const float* W = (m == 0) ? W0 : Wl + (size_t)(m - 1) * HF * HF;
    u16* Pm = P + (size_t)m * HF * HF;
    int lane = i & 63, kc = (i >> 6) & 3, t = i >> 8;
    int quad = lane >> 4, col = 16 * t + (lane & 15);
    #pragma unroll
    for (int j = 0; j < 8; ++j) {
        int k = kc * 32 + quad * 8 + j;
        Pm[(size_t)i * 8 + j] = f2b(W[k * HF + col]);
    }
}

// ======================= MFMA GEMM (+bias, + optional fused alpha dots) ==========
// block = 256 (4 waves); wave w owns rows m0+16w..+15, all 128 cols (8 n-tiles).
// C/D layout: col = lane&15 (in tile), row = quad*4 + reg
template<bool A32>
__global__ __launch_bounds__(256) void k_gemm_mfma(const u16* __restrict__ Ab,
                                                   const float* __restrict__ Af,
                                                   const u16* __restrict__ Bp,
                                                   const float* __restrict__ bias,
                                                   const float* __restrict__ a_s,
                                                   const float* __restrict__ a_d,
                                                   float* __restrict__ as_,
                                                   float* __restrict__ ad_,
                                                   u16* __restrict__ C, int M) {
    int lane = threadIdx.x & 63;
    int wave = threadIdx.x >> 6;
    int quad = lane >> 4, l16 = lane & 15;
    int m0 = blockIdx.x * 64 + wave * 16;
    int arow = m0 + l16;
    bool aval = arow < M;
    const bf16x8* Av = A32 ? nullptr : (const bf16x8*)(Ab + (size_t)arow * HF);
    const bf16x8* Bv = (const bf16x8*)Bp;
    f32x4 acc[8] = {};

    #pragma unroll
    for (int kc = 0; kc < 4; ++kc) {
        bf16x8 a = {};
        if (aval) {
            if constexpr (A32) {
                const float* ap = Af + (size_t)arow * HF + kc * 32 + quad * 8;
                float4 f0 = *(const float4*)ap;
                float4 f1 = *(const float4*)(ap + 4);
                a[0] = (short)f2b(f0.x); a[1] = (short)f2b(f0.y);
                a[2] = (short)f2b(f0.z); a[3] = (short)f2b(f0.w);
                a[4] = (short)f2b(f1.x); a[5] = (short)f2b(f1.y);
                a[6] = (short)f2b(f1.z); a[7] = (short)f2b(f1.w);
            } else {
                a = Av[kc * 4 + quad];
            }
        }
        #pragma unroll
        for (int t = 0; t < 8; ++t)
            acc[t] = __builtin_amdgcn_mfma_f32_16x16x32_bf16(a, Bv[t * 256 + kc * 64 + lane],
                                                             acc[t], 0, 0, 0);
    }

    int orow0 = m0 + quad * 4;
    #pragma unroll
    for (int t = 0; t < 8; ++t) {
        float b4 = bias ? bias[t * 16 + l16] : 0.f;
        #pragma unroll
        for (int r = 0; r < 4; ++r) {
            int orow = orow0 + r;
            if (orow < M) C[(size_t)orow * HF + t * 16 + l16] = f2b(acc[t][r] + b4);
        }
    }

    // fused attention dots: as_[row] = hp[row].a_s, ad_[row] = hp[row].a_d
    if (as_) {
        float avs[8], avd[8];
        #pragma unroll
        for (int t = 0; t < 8; ++t) {
            avs[t] = a_s[t * 16 + l16];
            avd[t] = a_d[t * 16 + l16];
        }
        #pragma unroll
        for (int r = 0; r < 4; ++r) {
            float ps = 0.f, pd = 0.f;
            #pragma unroll
            for (int t = 0; t < 8; ++t) {
                ps = fmaf(acc[t][r], avs[t], ps);
                pd = fmaf(acc[t][r], avd[t], pd);
            }
            #pragma unroll
            for (int o = 1; o < 16; o <<= 1) {
                ps += __shfl_xor(ps, o);
                pd += __shfl_xor(pd, o);
            }
            int row = orow0 + r;
            if (l16 == 0 && row < M) { as_[row] = ps; ad_[row] = pd; }
        }
    }
}

// ======================= per-dst softmax aggregation (bf16 gather) ==========
// Pass 2: half-wave per edge (32 lanes x 8B = one 256B row), 2 edges per load
// group, unroll x4 -> 8 rows in flight. Halves combined via shfl_xor(32).
__global__ __launch_bounds__(256) void k_agg(const int* __restrict__ rowbeg,
                                             const int* __restrict__ rowend,
                                             const int* __restrict__ colidx,
                                             const u16* __restrict__ hpb,
                                             const float* __restrict__ as_,
                                             const float* __restrict__ ad_,
                                             const float* __restrict__ bl,
                                             u16* __restrict__ hout,
                                             int n, int relu) {
    int wave = (blockIdx.x * 256 + threadIdx.x) >> 6;
    int lane = threadIdx.x & 63;
    if (wave >= n) return;
    int beg = rowbeg[wave], end = rowend[wave];
    int deg = end - beg;
    float adi = ad_[wave];

    // lane t owns edge t (first 64)
    int  srcl = (lane < deg) ? colidx[beg + lane] : 0;
    float el = -1e30f;
    if (lane < deg) {
        float e = as_[srcl] + adi;
        el = e > 0.f ? e : NEG * e;
    }

    float m = el;
    for (int jj = beg + 64 + lane; jj < end; jj += 64) {
        float e = as_[colidx[jj]] + adi;
        e = e > 0.f ? e : NEG * e;
        m = fmaxf(m, e);
    }
    #pragma unroll
    for (int off = 32; off; off >>= 1) m = fmaxf(m, __shfl_xor(m, off));

    float ex = (lane < deg) ? __expf(el - m) : 0.f;
    float ssum = ex;
    for (int jj = beg + 64 + lane; jj < end; jj += 64) {
        float e = as_[colidx[jj]] + adi;
        e = e > 0.f ? e : NEG * e;
        ssum += __expf(e - m);
    }
    #pragma unroll
    for (int off = 32; off; off >>= 1) ssum += __shfl_xor(ssum, off);
    float inv = 1.f / ssum;
    float wl = ex * inv;        // this lane's edge weight

    // ---- pass 2 ----
    int hl = lane & 31;         // feature group: feats hl*4 .. hl*4+3
    int half = lane >> 5;       // which edge of the pair this half-wave takes
    float a0 = 0.f, a1 = 0.f, a2 = 0.f, a3 = 0.f;
    int cnt = deg < 64 ? deg : 64;
    int npair = (cnt + 1) >> 1;

    int p = 0;
    for (; p + 4 <= npair; p += 4) {
        #pragma unroll
        for (int i = 0; i < 4; ++i) {
            int e  = 2 * (p + i) + half;
            int ec = e < cnt ? e : cnt - 1;
            int   s = __shfl(srcl, ec);
            float w = (e < cnt) ? __shfl(wl, ec) : 0.f;
            uint2 v = ((const uint2*)(hpb + (size_t)s * HF))[hl];
            a0 = fmaf(w, blo(v.x), a0); a1 = fmaf(w, bhi(v.x), a1);
            a2 = fmaf(w, blo(v.y), a2); a3 = fmaf(w, bhi(v.y), a3);
        }
    }
    for (; p < npair; ++p) {
        int e  = 2 * p + half;
        int ec = e < cnt ? e : cnt - 1;
        int   s = __shfl(srcl, ec);
        float w = (e < cnt) ? __shfl(wl, ec) : 0.f;
        uint2 v = ((const uint2*)(hpb + (size_t)s * HF))[hl];
        a0 = fmaf(w, blo(v.x), a0); a1 = fmaf(w, bhi(v.x), a1);
        a2 = fmaf(w, blo(v.y), a2); a3 = fmaf(w, bhi(v.y), a3);
    }
    // rare deg>64 tail: half 0 only (avoids double count after combine)
    for (int jj = beg + 64; jj < end; ++jj) {
        int srcn = colidx[jj];
        float e = as_[srcn] + adi;
        e = e > 0.f ? e : NEG * e;
        float w = (half == 0) ? __expf(e - m) * inv : 0.f;
        uint2 v = ((const uint2*)(hpb + (size_t)srcn * HF))[hl];
        a0 = fmaf(w, blo(v.x), a0); a1 = fmaf(w, bhi(v.x), a1);
        a2 = fmaf(w, blo(v.y), a2); a3 = fmaf(w, bhi(v.y), a3);
    }

    // combine halves
    a0 += __shfl_xor(a0, 32); a1 += __shfl_xor(a1, 32);
    a2 += __shfl_xor(a2, 32); a3 += __shfl_xor(a3, 32);

    if (half == 0) {
        float4 bb = ((const float4*)bl)[hl];
        a0 += bb.x; a1 += bb.y; a2 += bb.z; a3 += bb.w;
        if (relu) {
            a0 = fmaxf(a0, 0.f); a1 = fmaxf(a1, 0.f);
            a2 = fmaxf(a2, 0.f); a3 = fmaxf(a3, 0.f);
        }
        uint2 o;
        o.x = ((u32)f2b(a1) << 16) | (u32)f2b(a0);
        o.y = ((u32)f2b(a3) << 16) | (u32)f2b(a2);
        ((uint2*)(hout + (size_t)wave * HF))[hl] = o;
    }
}

// ======================= pooling over sorted batch (bf16 h, fp32 accum) ==========
#define PROWS 128
__global__ __launch_bounds__(128) void k_pool(const u16* __restrict__ hb,
                                              const int* __restrict__ batch,
                                              float* __restrict__ pooled, int n) {
    int r0 = blockIdx.x * PROWS;
    int r1 = min(r0 + PROWS, n);
    if (r0 >= r1) return;
    int t = threadIdx.x;
    int cur = batch[r0];
    float acc = 0.f;
    for (int i = r0; i < r1; ++i) {
        int b = batch[i];
        if (b != cur) {
            atomicAdd(&pooled[cur * HF + t], acc);
            acc = 0.f;
            cur = b;
        }
        acc += __builtin_bit_cast(float, (u32)hb[(size_t)i * HF + t] << 16);
    }
    atomicAdd(&pooled[cur * HF + t], acc);
}

__global__ void k_final(const float* __restrict__ pooled, const float* __restrict__ Wf,
                        const float* __restrict__ bf, float* __restrict__ out) {
    int g = blockIdx.x, o = threadIdx.x;   // 64 threads
    float acc = bf[o];
    #pragma unroll 8
    for (int k = 0; k < HF; ++k) acc = fmaf(pooled[g * HF + k], Wf[k * OUTF + o], acc);
    out[g * OUTF + o] = acc;
}

// ======================= launch =======================
extern "C" void kernel_launch(void* const* d_in, const int* in_sizes, int n_in,
                              void* d_out, int out_size, void* d_ws, size_t ws_size,
                              hipStream_t stream) {
    const float* x      = (const float*)d_in[0];
    const int*   edge   = (const int*)d_in[1];
    const int*   batch  = (const int*)d_in[2];
    const float* W0     = (const float*)d_in[3];
    const float* b0     = (const float*)d_in[4];
    const float* Wl     = (const float*)d_in[5];
    const float* a_src  = (const float*)d_in[6];
    const float* a_dst  = (const float*)d_in[7];
    const float* bl     = (const float*)d_in[8];
    const float* Wf     = (const float*)d_in[9];
    const float* bf     = (const float*)d_in[10];
    float* out = (float*)d_out;

    const int N  = in_sizes[2];
    const int E  = in_sizes[1] / 2;
    const int Et = E + N;
    const int L  = 3;
    const int NB = (N + 255) >> 8;               // buckets (<= 256)

    char* ws = (char*)d_ws;
    size_t off = 0;
    auto alloc = [&](size_t bytes) { char* p = ws + off; off += (bytes + 255) & ~(size_t)255; return p; };
    u16*   hb      = (u16*)alloc((size_t)N * HF * 2);
    u16*   hpb     = (u16*)alloc((size_t)N * HF * 2);
    u16*   Wp      = (u16*)alloc((size_t)4 * HF * HF * 2);
    float* as_     = (float*)alloc((size_t)N * 4);
    float* ad_     = (float*)alloc((size_t)N * 4);
    int*   rowbeg  = (int*)alloc((size_t)N * 4);
    int*   rowend  = (int*)alloc((size_t)N * 4);
    int*   colidx  = (int*)alloc((size_t)NB * BCAP * 4);
    u32*   epart   = (u32*)alloc((size_t)NB * BCAP * 4);
    int*   bucketCur = (int*)alloc(256 * 4);
    float* pooled  = (float*)alloc((size_t)GCOUNT * HF * 4);
    (void)ws_size; (void)n_in; (void)out_size;

    const int wb4   = (N + 3) / 4;               // wave-per-node kernels
    const int gemmb = (N + 63) / 64;
    const int partb = (Et + CH - 1) / CH;

    const int* esrc = edge;
    const int* edst = edge + E;

    // --- pack weights (one launch, all 4 matrices) ---
    k_pack<<<32, 256, 0, stream>>>(W0, Wl, Wp);

    // --- bucketed dst-CSR build (reused across all 3 layers) + pooled zero ---
    k_binit<<<33, 256, 0, stream>>>(bucketCur, pooled);
    k_bpart<<<partb, 256, 0, stream>>>(esrc, edst, bucketCur, epart, E, Et);
    k_bcsr<<<NB, 256, 0, stream>>>(epart, bucketCur, rowbeg, rowend, colidx, N);

    // --- h = x @ W0 + b0 (fp32 A, fused cvt) ---
    k_gemm_mfma<true><<<gemmb, 256, 0, stream>>>(nullptr, x, Wp, b0,
                                                 nullptr, nullptr, nullptr, nullptr, hb, N);

    // --- GAT layers (alpha dots fused into GEMM epilogue) ---
    for (int l = 0; l < L; ++l) {
        k_gemm_mfma<false><<<gemmb, 256, 0, stream>>>(hb, nullptr,
                                                      Wp + (size_t)(l + 1) * HF * HF, nullptr,
                                                      a_src + l * HF, a_dst + l * HF,
                                                      as_, ad_, hpb, N);
        k_agg<<<wb4, 256, 0, stream>>>(rowbeg, rowend, colidx, hpb, as_, ad_, bl + l * HF, hb, N,
                                       (l < L - 1) ? 1 : 0);
    }

    // --- pooling + final linear ---
    k_pool<<<(N + PROWS - 1) / PROWS, 128, 0, stream>>>(hb, batch, pooled, N);
    k_final<<<GCOUNT, OUTF, 0, stream>>>(pooled, Wf, bf, out);
}